// Round 1
// baseline (4690.688 us; speedup 1.0000x reference)
//
#include <hip/hip_runtime.h>
#include <cstddef>

// ---- problem constants (from reference) ----
#define N_U   100000
#define N_I   50000
#define DD    64
#define NNZ_  1000000
#define LL    2
#define TEMP_ 0.2f
#define LAM1  0.2f
#define DROP_ 0.1f
#define EPS_  0.05f
#define BB    2048

__device__ __forceinline__ float leaky(float x) { return x >= 0.0f ? x : 0.5f * x; }

__device__ __forceinline__ float waveReduceSum(float v) {
#pragma unroll
  for (int m = 32; m >= 1; m >>= 1) v += __shfl_xor(v, m, 64);
  return v;
}

// ---------------------------------------------------------------------------
// SpMM with sparse dropout: Z[seg[e]] += (vals[e]*keep/0.9) * E[gat[e]]
// 16 threads per edge, float4 per thread, hardware f32 atomics.
// ---------------------------------------------------------------------------
__global__ void spmm_edge(const float* __restrict__ vals,
                          const float* __restrict__ dr,
                          const int*   __restrict__ seg,
                          const int*   __restrict__ gat,
                          const float* __restrict__ E,
                          float*       __restrict__ Z,
                          int nnz) {
  int t = blockIdx.x * blockDim.x + threadIdx.x;
  int e = t >> 4;
  if (e >= nnz) return;
  float dv = (dr[e] >= DROP_) ? vals[e] * (1.0f / (1.0f - DROP_)) : 0.0f;
  if (dv == 0.0f) return;
  int l4 = (t & 15) * 4;
  int g = gat[e], sg = seg[e];
  const float4 ev = *(const float4*)(E + (size_t)g * DD + l4);
  float* zp = Z + (size_t)sg * DD + l4;
  unsafeAtomicAdd(zp + 0, dv * ev.x);
  unsafeAtomicAdd(zp + 1, dv * ev.y);
  unsafeAtomicAdd(zp + 2, dv * ev.z);
  unsafeAtomicAdd(zp + 3, dv * ev.w);
}

// ---------------------------------------------------------------------------
// C[64][64] += A[64][N] (row-major, stride N)  @  B[N][64]
// Each block owns a contiguous j-span; 16 accumulators/thread; atomic finish.
// ---------------------------------------------------------------------------
__global__ void gemm_at(const float* __restrict__ A,
                        const float* __restrict__ B,
                        float*       __restrict__ C,
                        int N) {
  int d  = threadIdx.x & 63;
  int r0 = (threadIdx.x >> 6) * 16;
  int span = (N + gridDim.x - 1) / gridDim.x;
  int j0 = blockIdx.x * span;
  int j1 = min(j0 + span, N);
  float acc[16];
#pragma unroll
  for (int i = 0; i < 16; ++i) acc[i] = 0.0f;
  for (int j = j0; j < j1; ++j) {
    float b = B[(size_t)j * DD + d];
#pragma unroll
    for (int i = 0; i < 16; ++i)
      acc[i] += A[(size_t)(r0 + i) * N + j] * b;
  }
#pragma unroll
  for (int i = 0; i < 16; ++i)
    unsafeAtomicAdd(&C[(r0 + i) * DD + d], acc[i]);
}

// ---------------------------------------------------------------------------
// out = base + leaky(Z)   (out may alias Z, same element per thread)
// ---------------------------------------------------------------------------
__global__ void combine_kernel(const float4* __restrict__ base,
                               const float4* __restrict__ Z,
                               float4*       __restrict__ out,
                               int n4) {
  int t = blockIdx.x * blockDim.x + threadIdx.x;
  if (t >= n4) return;
  float4 b = base[t], z = Z[t];
  float4 r;
  r.x = b.x + leaky(z.x);
  r.y = b.y + leaky(z.y);
  r.z = b.z + leaky(z.z);
  r.w = b.w + leaky(z.w);
  out[t] = r;
}

// ---------------------------------------------------------------------------
// h = l2norm(leaky(((svd + sign(svd)*l2norm(noise)*EPS) * s)[ids] @ M)) @ W
// One wave per batch row; lane = both input index k and output dim d.
// ---------------------------------------------------------------------------
__global__ void h_kernel(const float* __restrict__ svd,
                         const float* __restrict__ noise,
                         const float* __restrict__ sdiag,
                         const float* __restrict__ M,   // [64][64] vt_ei / ut_eu
                         const float* __restrict__ W,   // [64][64]
                         const int*   __restrict__ ids,
                         float*       __restrict__ hout) {
  int wid  = threadIdx.x >> 6;
  int lane = threadIdx.x & 63;
  int i = blockIdx.x * 4 + wid;
  int id = ids[i];
  float nz = noise[(size_t)id * DD + lane];
  float sv = svd[(size_t)id * DD + lane];
  float ns = waveReduceSum(nz * nz);
  float den = fmaxf(sqrtf(ns), 1e-12f);
  float sgn = (sv > 0.0f) ? 1.0f : ((sv < 0.0f) ? -1.0f : 0.0f);
  float gin = (sv + sgn * (nz / den) * EPS_) * sdiag[lane];

  float acc = 0.0f;
#pragma unroll
  for (int k = 0; k < 64; ++k)
    acc += __shfl(gin, k, 64) * M[k * DD + lane];
  acc = leaky(acc);

  float ss = waveReduceSum(acc * acc);
  float gn = acc / fmaxf(sqrtf(ss), 1e-12f);

  float h = 0.0f;
#pragma unroll
  for (int k = 0; k < 64; ++k)
    h += __shfl(gn, k, 64) * W[k * DD + lane];
  hout[(size_t)i * DD + lane] = h;
}

// ---------------------------------------------------------------------------
// InfoNCE score: per row i, neg = sum_j exp(h1_i.h2_j/T), pos = h1_i.h2_i,
// loss += -log(exp(pos/T)/(neg+1e-8)+1e-8) * mask_i
// One wave per i (4 waves/block); h2 tiled through LDS.
// ---------------------------------------------------------------------------
__global__ void score_kernel(const float* __restrict__ h1,
                             const float* __restrict__ h2,
                             const float* __restrict__ mask_raw,
                             float*       __restrict__ loss_acc) {
  __shared__ float sH2[64][65];
  int wid  = threadIdx.x >> 6;
  int lane = threadIdx.x & 63;
  int i = blockIdx.x * 4 + wid;
  float h1v = h1[(size_t)i * DD + lane];
  float h2v = h2[(size_t)i * DD + lane];
  float negacc = 0.0f;

  for (int jt = 0; jt < BB; jt += 64) {
    __syncthreads();
#pragma unroll
    for (int t = 0; t < 16; ++t) {
      int lin = threadIdx.x + t * 256;
      sH2[lin >> 6][lin & 63] = h2[(size_t)(jt + (lin >> 6)) * DD + (lin & 63)];
    }
    __syncthreads();
    float dot = 0.0f;
#pragma unroll
    for (int d = 0; d < 64; ++d) {
      float h1d = __shfl(h1v, d, 64);
      dot += h1d * sH2[lane][d];
    }
    negacc += expf(dot * (1.0f / TEMP_));
  }
  float neg = waveReduceSum(negacc);
  float pos = waveReduceSum(h1v * h2v);
  if (lane == 0) {
    float ps = expf(pos * (1.0f / TEMP_));
    float m  = (mask_raw[i] > 0.5f) ? 1.0f : 0.0f;
    float li = -logf(ps / (neg + 1e-8f) + 1e-8f) * m;
    unsafeAtomicAdd(loss_acc, li);
  }
}

// ---------------------------------------------------------------------------
// BPR: sum relu(1 - <Eu[uid],Ei[pos]> + <Eu[uid],Ei[neg]>)
// Eu = Eu0 + EU1 + EU2; Ei = Ei0 + EI1 + EI2. One wave per batch row.
// ---------------------------------------------------------------------------
__global__ void bpr_kernel(const float* __restrict__ Eu0, const float* __restrict__ EU1,
                           const float* __restrict__ EU2,
                           const float* __restrict__ Ei0, const float* __restrict__ EI1,
                           const float* __restrict__ EI2,
                           const int* __restrict__ uids, const int* __restrict__ pos,
                           const int* __restrict__ neg,
                           float* __restrict__ acc_r) {
  int wid  = threadIdx.x >> 6;
  int lane = threadIdx.x & 63;
  int i = blockIdx.x * 4 + wid;
  size_t u = (size_t)uids[i] * DD + lane;
  size_t p = (size_t)pos[i]  * DD + lane;
  size_t n = (size_t)neg[i]  * DD + lane;
  float ue = Eu0[u] + EU1[u] + EU2[u];
  float pe = Ei0[p] + EI1[p] + EI2[p];
  float ne = Ei0[n] + EI1[n] + EI2[n];
  float ps = waveReduceSum(ue * pe);
  float ns = waveReduceSum(ue * ne);
  if (lane == 0) {
    float v = fmaxf(1.0f - ps + ns, 0.0f);
    unsafeAtomicAdd(acc_r, v);
  }
}

__global__ void finalize_kernel(const float* __restrict__ acc, float* __restrict__ out) {
  float lr = acc[0] / (float)BB;
  float ls = acc[1];
  out[0] = lr + LAM1 * ls;
  out[1] = lr;
  out[2] = ls;
}

// ---------------------------------------------------------------------------
extern "C" void kernel_launch(void* const* d_in, const int* in_sizes, int n_in,
                              void* d_out, int out_size, void* d_ws, size_t ws_size,
                              hipStream_t stream) {
  const float* E_u_0   = (const float*)d_in[0];
  const float* E_i_0   = (const float*)d_in[1];
  const float* svd_u   = (const float*)d_in[2];
  const float* svd_v   = (const float*)d_in[3];
  const float* sdiag   = (const float*)d_in[4];
  const float* ut      = (const float*)d_in[5];
  const float* vt      = (const float*)d_in[6];
  const float* W_u     = (const float*)d_in[7];
  const float* W_i     = (const float*)d_in[8];
  const float* adjv    = (const float*)d_in[9];
  const float* dropr   = (const float*)d_in[10];
  const float* noise_u1= (const float*)d_in[11];
  const float* noise_v1= (const float*)d_in[12];
  const float* noise_u2= (const float*)d_in[13];
  const float* noise_v2= (const float*)d_in[14];
  const float* u_mask  = (const float*)d_in[15];
  const float* i_mask  = (const float*)d_in[16];
  const int*   rows    = (const int*)d_in[17];
  const int*   cols    = (const int*)d_in[18];
  const int*   uids    = (const int*)d_in[19];
  const int*   iids    = (const int*)d_in[20];
  const int*   pos     = (const int*)d_in[21];
  const int*   neg     = (const int*)d_in[22];
  float* out = (float*)d_out;

  // ---- workspace layout (floats); total ~19.5M floats ≈ 78 MB ----
  float* ws    = (float*)d_ws;
  float* ZU    = ws;                       // 6,400,000  (becomes E_u_2 in-place)
  float* EU1   = ZU  + (size_t)N_U * DD;   // 6,400,000
  float* ZI    = EU1 + (size_t)N_U * DD;   // 3,200,000  (becomes E_i_2 in-place)
  float* EI1   = ZI  + (size_t)N_I * DD;   // 3,200,000
  float* vtei  = EI1 + (size_t)N_I * DD;   // 2 * 4096
  float* uteu  = vtei + 2 * DD * DD;       // 2 * 4096
  float* accs  = uteu + 2 * DD * DD;       // 16 (acc[0]=loss_r sum, acc[1]=loss_s)
  float* h1    = accs + 16;                // 131072
  float* h2    = h1 + (size_t)BB * DD;     // 131072

  const int TB = 256;
  dim3 blk(TB);
  int spmm_grid = (NNZ_ * 16 + TB - 1) / TB;
  int comb_u4 = (N_U * DD) / 4, comb_i4 = (N_I * DD) / 4;
  int comb_gu = (comb_u4 + TB - 1) / TB, comb_gi = (comb_i4 + TB - 1) / TB;
  int row_grid = BB / 4;  // wave-per-row kernels

  // zero accumulation buffers
  hipMemsetAsync(ZU, 0, (size_t)N_U * DD * sizeof(float), stream);
  hipMemsetAsync(ZI, 0, (size_t)N_I * DD * sizeof(float), stream);
  hipMemsetAsync(vtei, 0, (4 * DD * DD + 16) * sizeof(float), stream);  // vtei,uteu,accs

  // ---- layer 1 ----
  gemm_at<<<256, blk, 0, stream>>>(vt, E_i_0, vtei, N_I);
  gemm_at<<<256, blk, 0, stream>>>(ut, E_u_0, uteu, N_U);
  spmm_edge<<<spmm_grid, blk, 0, stream>>>(adjv, dropr + 0 * (size_t)NNZ_, rows, cols, E_i_0, ZU, NNZ_);
  spmm_edge<<<spmm_grid, blk, 0, stream>>>(adjv, dropr + 1 * (size_t)NNZ_, cols, rows, E_u_0, ZI, NNZ_);
  combine_kernel<<<comb_gu, blk, 0, stream>>>((const float4*)E_u_0, (const float4*)ZU, (float4*)EU1, comb_u4);
  combine_kernel<<<comb_gi, blk, 0, stream>>>((const float4*)E_i_0, (const float4*)ZI, (float4*)EI1, comb_i4);

  // ---- layer 2 ----
  hipMemsetAsync(ZU, 0, (size_t)N_U * DD * sizeof(float), stream);
  hipMemsetAsync(ZI, 0, (size_t)N_I * DD * sizeof(float), stream);
  gemm_at<<<256, blk, 0, stream>>>(vt, EI1, vtei + DD * DD, N_I);
  gemm_at<<<256, blk, 0, stream>>>(ut, EU1, uteu + DD * DD, N_U);
  spmm_edge<<<spmm_grid, blk, 0, stream>>>(adjv, dropr + 2 * (size_t)NNZ_, rows, cols, EI1, ZU, NNZ_);
  spmm_edge<<<spmm_grid, blk, 0, stream>>>(adjv, dropr + 3 * (size_t)NNZ_, cols, rows, EU1, ZI, NNZ_);
  // in-place: ZU = EU1 + leaky(ZU)  (= E_u_2), same for items
  combine_kernel<<<comb_gu, blk, 0, stream>>>((const float4*)EU1, (const float4*)ZU, (float4*)ZU, comb_u4);
  combine_kernel<<<comb_gi, blk, 0, stream>>>((const float4*)EI1, (const float4*)ZI, (float4*)ZI, comb_i4);

  // ---- contrastive losses (only at gathered ids: 2048 rows per view) ----
  for (int l = 0; l < LL; ++l) {
    const float* Mv = vtei + l * DD * DD;
    const float* Mu = uteu + l * DD * DD;
    // user side
    h_kernel<<<row_grid, blk, 0, stream>>>(svd_u, noise_u1, sdiag, Mv, W_u + l * DD * DD, uids, h1);
    h_kernel<<<row_grid, blk, 0, stream>>>(svd_u, noise_u2, sdiag, Mv, W_u + l * DD * DD, uids, h2);
    score_kernel<<<row_grid, blk, 0, stream>>>(h1, h2, u_mask + l * BB, accs + 1);
    // item side
    h_kernel<<<row_grid, blk, 0, stream>>>(svd_v, noise_v1, sdiag, Mu, W_i + l * DD * DD, iids, h1);
    h_kernel<<<row_grid, blk, 0, stream>>>(svd_v, noise_v2, sdiag, Mu, W_i + l * DD * DD, iids, h2);
    score_kernel<<<row_grid, blk, 0, stream>>>(h1, h2, i_mask + l * BB, accs + 1);
  }

  // ---- BPR loss ----
  bpr_kernel<<<row_grid, blk, 0, stream>>>(E_u_0, EU1, ZU, E_i_0, EI1, ZI,
                                           uids, pos, neg, accs);

  finalize_kernel<<<1, 1, 0, stream>>>(accs, out);
}

// Round 2
// 2202.063 us; speedup vs baseline: 2.1301x; 2.1301x over previous
//
#include <hip/hip_runtime.h>
#include <cstddef>

// ---- problem constants (from reference) ----
#define N_U   100000
#define N_I   50000
#define DD    64
#define NNZ_  1000000
#define LL    2
#define TEMP_ 0.2f
#define LAM1  0.2f
#define DROP_ 0.1f
#define EPS_  0.05f
#define BB    2048

__device__ __forceinline__ float leaky(float x) { return x >= 0.0f ? x : 0.5f * x; }

__device__ __forceinline__ float waveReduceSum(float v) {
#pragma unroll
  for (int m = 32; m >= 1; m >>= 1) v += __shfl_xor(v, m, 64);
  return v;
}

// ===========================================================================
// CSR build: histogram -> scan (3-phase) -> scatter
// ===========================================================================
__global__ void hist_kernel(const int* __restrict__ rows, const int* __restrict__ cols,
                            int* __restrict__ deg_u, int* __restrict__ deg_i, int nnz) {
  int e = blockIdx.x * blockDim.x + threadIdx.x;
  if (e >= nnz) return;
  atomicAdd(&deg_u[rows[e]], 1);
  atomicAdd(&deg_i[cols[e]], 1);
}

// chunk = 1024 elements per block (256 thr x 4). tmp = per-block inclusive scan.
__global__ void scan1(const int* __restrict__ in, int* __restrict__ tmp,
                      int* __restrict__ partial, int n) {
  __shared__ int s[256];
  int t = threadIdx.x;
  int base = blockIdx.x * 1024;
  int v[4]; int tsum = 0;
#pragma unroll
  for (int k = 0; k < 4; ++k) {
    int idx = base + t * 4 + k;
    v[k] = (idx < n) ? in[idx] : 0;
    tsum += v[k];
  }
  s[t] = tsum;
  __syncthreads();
  for (int ofs = 1; ofs < 256; ofs <<= 1) {
    int x = (t >= ofs) ? s[t - ofs] : 0;
    __syncthreads();
    s[t] += x;
    __syncthreads();
  }
  if (t == 255) partial[blockIdx.x] = s[255];
  int run = (t == 0) ? 0 : s[t - 1];
#pragma unroll
  for (int k = 0; k < 4; ++k) {
    run += v[k];
    int idx = base + t * 4 + k;
    if (idx < n) tmp[idx] = run;
  }
}

// single block; nb <= 256. makes partial[] exclusive.
__global__ void scan2(int* __restrict__ partial, int nb) {
  __shared__ int s[256];
  int t = threadIdx.x;
  s[t] = (t < nb) ? partial[t] : 0;
  __syncthreads();
  for (int ofs = 1; ofs < 256; ofs <<= 1) {
    int x = (t >= ofs) ? s[t - ofs] : 0;
    __syncthreads();
    s[t] += x;
    __syncthreads();
  }
  if (t < nb) partial[t] = (t == 0) ? 0 : s[t - 1];
}

__global__ void scan3(const int* __restrict__ tmp, const int* __restrict__ partial,
                      int* __restrict__ off, int n) {
  int i = blockIdx.x * blockDim.x + threadIdx.x;
  if (i == 0) off[0] = 0;
  if (i < n) off[i + 1] = tmp[i] + partial[i >> 10];
}

__global__ void scatter_kernel(const int* __restrict__ rows, const int* __restrict__ cols,
                               const int* __restrict__ off_u, const int* __restrict__ off_i,
                               int* __restrict__ cur_u, int* __restrict__ cur_i,
                               int* __restrict__ el_u, int* __restrict__ el_i, int nnz) {
  int e = blockIdx.x * blockDim.x + threadIdx.x;
  if (e >= nnz) return;
  int r = rows[e];
  int p = atomicAdd(&cur_u[r], 1);
  el_u[off_u[r] + p] = e;
  int c = cols[e];
  int q = atomicAdd(&cur_i[c], 1);
  el_i[off_i[c] + q] = e;
}

// ===========================================================================
// Row-wise SpMM (no atomics), fused with residual + leaky:
//   out[r] = base[r] + leaky( sum_{e in row r} dv(e) * Esrc[gat[e]] )
// One wave per row, lane = dim.
// ===========================================================================
__global__ void spmm_rows(const int* __restrict__ off, const int* __restrict__ elist,
                          const int* __restrict__ gat,
                          const float* __restrict__ vals, const float* __restrict__ dr,
                          const float* __restrict__ Esrc, const float* __restrict__ base,
                          float* __restrict__ out, int n) {
  int wid = threadIdx.x >> 6, lane = threadIdx.x & 63;
  int r = blockIdx.x * 4 + wid;
  if (r >= n) return;
  int i0 = off[r], i1 = off[r + 1];
  float acc = 0.0f;
  int i = i0;
  for (; i + 1 < i1; i += 2) {
    int e0 = elist[i], e1 = elist[i + 1];
    int g0 = gat[e0], g1 = gat[e1];
    float dv0 = (dr[e0] >= DROP_) ? vals[e0] * (1.0f / (1.0f - DROP_)) : 0.0f;
    float dv1 = (dr[e1] >= DROP_) ? vals[e1] * (1.0f / (1.0f - DROP_)) : 0.0f;
    acc += dv0 * Esrc[(size_t)g0 * DD + lane];
    acc += dv1 * Esrc[(size_t)g1 * DD + lane];
  }
  if (i < i1) {
    int e0 = elist[i];
    int g0 = gat[e0];
    float dv0 = (dr[e0] >= DROP_) ? vals[e0] * (1.0f / (1.0f - DROP_)) : 0.0f;
    acc += dv0 * Esrc[(size_t)g0 * DD + lane];
  }
  size_t o = (size_t)r * DD + lane;
  out[o] = base[o] + leaky(acc);
}

// Same, but only for gathered batch rows; compact output [nb][64].
__global__ void spmm_batch(const int* __restrict__ ids,
                           const int* __restrict__ off, const int* __restrict__ elist,
                           const int* __restrict__ gat,
                           const float* __restrict__ vals, const float* __restrict__ dr,
                           const float* __restrict__ Esrc, const float* __restrict__ base,
                           float* __restrict__ out, int nb) {
  int wid = threadIdx.x >> 6, lane = threadIdx.x & 63;
  int i = blockIdx.x * 4 + wid;
  if (i >= nb) return;
  int r = ids[i];
  int i0 = off[r], i1 = off[r + 1];
  float acc = 0.0f;
  for (int j = i0; j < i1; ++j) {
    int e = elist[j];
    int g = gat[e];
    float dv = (dr[e] >= DROP_) ? vals[e] * (1.0f / (1.0f - DROP_)) : 0.0f;
    acc += dv * Esrc[(size_t)g * DD + lane];
  }
  out[(size_t)i * DD + lane] = base[(size_t)r * DD + lane] + leaky(acc);
}

// ===========================================================================
// C[64][64] += A[64][N] (row-major, stride N) @ B[N][64]
// ===========================================================================
__global__ void gemm_at(const float* __restrict__ A,
                        const float* __restrict__ B,
                        float*       __restrict__ C,
                        int N) {
  int d  = threadIdx.x & 63;
  int r0 = (threadIdx.x >> 6) * 16;
  int span = (N + gridDim.x - 1) / gridDim.x;
  int j0 = blockIdx.x * span;
  int j1 = min(j0 + span, N);
  float acc[16];
#pragma unroll
  for (int i = 0; i < 16; ++i) acc[i] = 0.0f;
  for (int j = j0; j < j1; ++j) {
    float b = B[(size_t)j * DD + d];
#pragma unroll
    for (int i = 0; i < 16; ++i)
      acc[i] += A[(size_t)(r0 + i) * N + j] * b;
  }
#pragma unroll
  for (int i = 0; i < 16; ++i)
    unsafeAtomicAdd(&C[(r0 + i) * DD + d], acc[i]);
}

// ===========================================================================
// h = l2norm(leaky(((svd + sign(svd)*l2norm(noise)*EPS)*s)[ids] @ M)) @ W
// ===========================================================================
__global__ void h_kernel(const float* __restrict__ svd,
                         const float* __restrict__ noise,
                         const float* __restrict__ sdiag,
                         const float* __restrict__ M,
                         const float* __restrict__ W,
                         const int*   __restrict__ ids,
                         float*       __restrict__ hout) {
  int wid  = threadIdx.x >> 6;
  int lane = threadIdx.x & 63;
  int i = blockIdx.x * 4 + wid;
  int id = ids[i];
  float nz = noise[(size_t)id * DD + lane];
  float sv = svd[(size_t)id * DD + lane];
  float ns = waveReduceSum(nz * nz);
  float den = fmaxf(sqrtf(ns), 1e-12f);
  float sgn = (sv > 0.0f) ? 1.0f : ((sv < 0.0f) ? -1.0f : 0.0f);
  float gin = (sv + sgn * (nz / den) * EPS_) * sdiag[lane];

  float acc = 0.0f;
#pragma unroll
  for (int k = 0; k < 64; ++k)
    acc += __shfl(gin, k, 64) * M[k * DD + lane];
  acc = leaky(acc);

  float ss = waveReduceSum(acc * acc);
  float gn = acc / fmaxf(sqrtf(ss), 1e-12f);

  float h = 0.0f;
#pragma unroll
  for (int k = 0; k < 64; ++k)
    h += __shfl(gn, k, 64) * W[k * DD + lane];
  hout[(size_t)i * DD + lane] = h;
}

// ===========================================================================
// InfoNCE score over the 2048x2048 similarity
// ===========================================================================
__global__ void score_kernel(const float* __restrict__ h1,
                             const float* __restrict__ h2,
                             const float* __restrict__ mask_raw,
                             float*       __restrict__ loss_acc) {
  __shared__ float sH2[64][65];
  int wid  = threadIdx.x >> 6;
  int lane = threadIdx.x & 63;
  int i = blockIdx.x * 4 + wid;
  float h1v = h1[(size_t)i * DD + lane];
  float h2v = h2[(size_t)i * DD + lane];
  float negacc = 0.0f;

  for (int jt = 0; jt < BB; jt += 64) {
    __syncthreads();
#pragma unroll
    for (int t = 0; t < 16; ++t) {
      int lin = threadIdx.x + t * 256;
      sH2[lin >> 6][lin & 63] = h2[(size_t)(jt + (lin >> 6)) * DD + (lin & 63)];
    }
    __syncthreads();
    float dot = 0.0f;
#pragma unroll
    for (int d = 0; d < 64; ++d) {
      float h1d = __shfl(h1v, d, 64);
      dot += h1d * sH2[lane][d];
    }
    negacc += expf(dot * (1.0f / TEMP_));
  }
  float neg = waveReduceSum(negacc);
  float pos = waveReduceSum(h1v * h2v);
  if (lane == 0) {
    float ps = expf(pos * (1.0f / TEMP_));
    float m  = (mask_raw[i] > 0.5f) ? 1.0f : 0.0f;
    float li = -logf(ps / (neg + 1e-8f) + 1e-8f) * m;
    unsafeAtomicAdd(loss_acc, li);
  }
}

// ===========================================================================
// BPR: u = E0+E1+E2(batched); pos/neg similarly.
// ===========================================================================
__global__ void bpr_kernel(const float* __restrict__ Eu0, const float* __restrict__ EU1,
                           const float* __restrict__ bu,
                           const float* __restrict__ Ei0, const float* __restrict__ EI1,
                           const float* __restrict__ bpos, const float* __restrict__ bneg,
                           const int* __restrict__ uids, const int* __restrict__ pos,
                           const int* __restrict__ neg,
                           float* __restrict__ acc_r) {
  int wid  = threadIdx.x >> 6;
  int lane = threadIdx.x & 63;
  int i = blockIdx.x * 4 + wid;
  size_t u = (size_t)uids[i] * DD + lane;
  size_t p = (size_t)pos[i]  * DD + lane;
  size_t n = (size_t)neg[i]  * DD + lane;
  size_t bi = (size_t)i * DD + lane;
  float ue = Eu0[u] + EU1[u] + bu[bi];
  float pe = Ei0[p] + EI1[p] + bpos[bi];
  float ne = Ei0[n] + EI1[n] + bneg[bi];
  float ps = waveReduceSum(ue * pe);
  float ns = waveReduceSum(ue * ne);
  if (lane == 0) {
    float v = fmaxf(1.0f - ps + ns, 0.0f);
    unsafeAtomicAdd(acc_r, v);
  }
}

__global__ void finalize_kernel(const float* __restrict__ acc, float* __restrict__ out) {
  float lr = acc[0] / (float)BB;
  float ls = acc[1];
  out[0] = lr + LAM1 * ls;
  out[1] = lr;
  out[2] = ls;
}

// ===========================================================================
extern "C" void kernel_launch(void* const* d_in, const int* in_sizes, int n_in,
                              void* d_out, int out_size, void* d_ws, size_t ws_size,
                              hipStream_t stream) {
  const float* E_u_0   = (const float*)d_in[0];
  const float* E_i_0   = (const float*)d_in[1];
  const float* svd_u   = (const float*)d_in[2];
  const float* svd_v   = (const float*)d_in[3];
  const float* sdiag   = (const float*)d_in[4];
  const float* ut      = (const float*)d_in[5];
  const float* vt      = (const float*)d_in[6];
  const float* W_u     = (const float*)d_in[7];
  const float* W_i     = (const float*)d_in[8];
  const float* adjv    = (const float*)d_in[9];
  const float* dropr   = (const float*)d_in[10];
  const float* noise_u1= (const float*)d_in[11];
  const float* noise_v1= (const float*)d_in[12];
  const float* noise_u2= (const float*)d_in[13];
  const float* noise_v2= (const float*)d_in[14];
  const float* u_mask  = (const float*)d_in[15];
  const float* i_mask  = (const float*)d_in[16];
  const int*   rows    = (const int*)d_in[17];
  const int*   cols    = (const int*)d_in[18];
  const int*   uids    = (const int*)d_in[19];
  const int*   iids    = (const int*)d_in[20];
  const int*   pos     = (const int*)d_in[21];
  const int*   neg     = (const int*)d_in[22];
  float* out = (float*)d_out;

  // ---- workspace layout ----
  float* ws   = (float*)d_ws;
  float* EU1  = ws;                          // 6,400,000 f
  float* EI1  = EU1 + (size_t)N_U * DD;      // 3,200,000 f
  float* bu   = EI1 + (size_t)N_I * DD;      // BB*64
  float* bpos = bu   + (size_t)BB * DD;      // BB*64
  float* bneg = bpos + (size_t)BB * DD;      // BB*64
  float* h1   = bneg + (size_t)BB * DD;      // BB*64
  float* h2   = h1   + (size_t)BB * DD;      // BB*64
  float* vtei = h2   + (size_t)BB * DD;      // 2*4096
  float* uteu = vtei + 2 * DD * DD;          // 2*4096
  float* accs = uteu + 2 * DD * DD;          // 16
  int* ip     = (int*)(accs + 16);
  int* el_u   = ip;                          // NNZ
  int* el_i   = el_u + NNZ_;                 // NNZ
  int* off_u  = el_i + NNZ_;                 // N_U+1
  int* off_i  = off_u + (N_U + 1);           // N_I+1
  int* deg_u  = off_i + (N_I + 1);           // N_U
  int* deg_i  = deg_u + N_U;                 // N_I
  int* cur_u  = deg_i + N_I;                 // N_U
  int* cur_i  = cur_u + N_U;                 // N_I
  int* stmp   = cur_i + N_I;                 // N_U (scan temp, reused)
  int* spart  = stmp + N_U;                  // 256

  const int TB = 256;
  dim3 blk(TB);
  int eg = (NNZ_ + TB - 1) / TB;
  int row_grid = BB / 4;

  // ---- zero counters / accumulators ----
  hipMemsetAsync(deg_u, 0, (size_t)(2 * N_U + 2 * N_I) * sizeof(int), stream); // deg_u,deg_i,cur_u,cur_i
  hipMemsetAsync(vtei, 0, (4 * DD * DD + 16) * sizeof(float), stream);         // vtei,uteu,accs

  // ---- CSR build (shared by both layers & directions) ----
  hist_kernel<<<eg, blk, 0, stream>>>(rows, cols, deg_u, deg_i, NNZ_);
  {
    int nb_u = (N_U + 1023) / 1024, nb_i = (N_I + 1023) / 1024;
    scan1<<<nb_u, blk, 0, stream>>>(deg_u, stmp, spart, N_U);
    scan2<<<1, blk, 0, stream>>>(spart, nb_u);
    scan3<<<(N_U + TB - 1) / TB, blk, 0, stream>>>(stmp, spart, off_u, N_U);
    scan1<<<nb_i, blk, 0, stream>>>(deg_i, stmp, spart, N_I);
    scan2<<<1, blk, 0, stream>>>(spart, nb_i);
    scan3<<<(N_I + TB - 1) / TB, blk, 0, stream>>>(stmp, spart, off_i, N_I);
  }
  scatter_kernel<<<eg, blk, 0, stream>>>(rows, cols, off_u, off_i, cur_u, cur_i,
                                         el_u, el_i, NNZ_);

  // ---- layer-1 small GEMMs (on E0) ----
  gemm_at<<<256, blk, 0, stream>>>(vt, E_i_0, vtei, N_I);
  gemm_at<<<256, blk, 0, stream>>>(ut, E_u_0, uteu, N_U);

  // ---- layer-1 full SpMM (fused residual+leaky): E1 = E0 + leaky(Z1) ----
  spmm_rows<<<(N_U + 3) / 4, blk, 0, stream>>>(off_u, el_u, cols, adjv,
      dropr + 0 * (size_t)NNZ_, E_i_0, E_u_0, EU1, N_U);
  spmm_rows<<<(N_I + 3) / 4, blk, 0, stream>>>(off_i, el_i, rows, adjv,
      dropr + 1 * (size_t)NNZ_, E_u_0, E_i_0, EI1, N_I);

  // ---- layer-2 small GEMMs (on E1) ----
  gemm_at<<<256, blk, 0, stream>>>(vt, EI1, vtei + DD * DD, N_I);
  gemm_at<<<256, blk, 0, stream>>>(ut, EU1, uteu + DD * DD, N_U);

  // ---- layer-2 SpMM only at batch rows: E2[id] = E1[id] + leaky(Z2[id]) ----
  spmm_batch<<<row_grid, blk, 0, stream>>>(uids, off_u, el_u, cols, adjv,
      dropr + 2 * (size_t)NNZ_, EI1, EU1, bu, BB);
  spmm_batch<<<row_grid, blk, 0, stream>>>(pos, off_i, el_i, rows, adjv,
      dropr + 3 * (size_t)NNZ_, EU1, EI1, bpos, BB);
  spmm_batch<<<row_grid, blk, 0, stream>>>(neg, off_i, el_i, rows, adjv,
      dropr + 3 * (size_t)NNZ_, EU1, EI1, bneg, BB);

  // ---- contrastive losses (only at gathered ids) ----
  for (int l = 0; l < LL; ++l) {
    const float* Mv = vtei + l * DD * DD;
    const float* Mu = uteu + l * DD * DD;
    h_kernel<<<row_grid, blk, 0, stream>>>(svd_u, noise_u1, sdiag, Mv, W_u + l * DD * DD, uids, h1);
    h_kernel<<<row_grid, blk, 0, stream>>>(svd_u, noise_u2, sdiag, Mv, W_u + l * DD * DD, uids, h2);
    score_kernel<<<row_grid, blk, 0, stream>>>(h1, h2, u_mask + l * BB, accs + 1);
    h_kernel<<<row_grid, blk, 0, stream>>>(svd_v, noise_v1, sdiag, Mu, W_i + l * DD * DD, iids, h1);
    h_kernel<<<row_grid, blk, 0, stream>>>(svd_v, noise_v2, sdiag, Mu, W_i + l * DD * DD, iids, h2);
    score_kernel<<<row_grid, blk, 0, stream>>>(h1, h2, i_mask + l * BB, accs + 1);
  }

  // ---- BPR ----
  bpr_kernel<<<row_grid, blk, 0, stream>>>(E_u_0, EU1, bu, E_i_0, EI1, bpos, bneg,
                                           uids, pos, neg, accs);

  finalize_kernel<<<1, 1, 0, stream>>>(accs, out);
}

// Round 3
// 1226.922 us; speedup vs baseline: 3.8231x; 1.7948x over previous
//
#include <hip/hip_runtime.h>
#include <cstddef>

// ---- problem constants (from reference) ----
#define N_U   100000
#define N_I   50000
#define DD    64
#define NNZ_  1000000
#define LL    2
#define TEMP_ 0.2f
#define LAM1  0.2f
#define DROP_ 0.1f
#define EPS_  0.05f
#define BB    2048
#define GEMM_BLOCKS 512

__device__ __forceinline__ float leaky(float x) { return x >= 0.0f ? x : 0.5f * x; }

__device__ __forceinline__ float waveReduceSum(float v) {
#pragma unroll
  for (int m = 32; m >= 1; m >>= 1) v += __shfl_xor(v, m, 64);
  return v;
}

// ===========================================================================
// CSR build: histogram -> scan (3-phase) -> scatter
// ===========================================================================
__global__ void hist_kernel(const int* __restrict__ rows, const int* __restrict__ cols,
                            int* __restrict__ deg_u, int* __restrict__ deg_i, int nnz) {
  int e = blockIdx.x * blockDim.x + threadIdx.x;
  if (e >= nnz) return;
  atomicAdd(&deg_u[rows[e]], 1);
  atomicAdd(&deg_i[cols[e]], 1);
}

__global__ void scan1(const int* __restrict__ in, int* __restrict__ tmp,
                      int* __restrict__ partial, int n) {
  __shared__ int s[256];
  int t = threadIdx.x;
  int base = blockIdx.x * 1024;
  int v[4]; int tsum = 0;
#pragma unroll
  for (int k = 0; k < 4; ++k) {
    int idx = base + t * 4 + k;
    v[k] = (idx < n) ? in[idx] : 0;
    tsum += v[k];
  }
  s[t] = tsum;
  __syncthreads();
  for (int ofs = 1; ofs < 256; ofs <<= 1) {
    int x = (t >= ofs) ? s[t - ofs] : 0;
    __syncthreads();
    s[t] += x;
    __syncthreads();
  }
  if (t == 255) partial[blockIdx.x] = s[255];
  int run = (t == 0) ? 0 : s[t - 1];
#pragma unroll
  for (int k = 0; k < 4; ++k) {
    run += v[k];
    int idx = base + t * 4 + k;
    if (idx < n) tmp[idx] = run;
  }
}

__global__ void scan2(int* __restrict__ partial, int nb) {
  __shared__ int s[256];
  int t = threadIdx.x;
  s[t] = (t < nb) ? partial[t] : 0;
  __syncthreads();
  for (int ofs = 1; ofs < 256; ofs <<= 1) {
    int x = (t >= ofs) ? s[t - ofs] : 0;
    __syncthreads();
    s[t] += x;
    __syncthreads();
  }
  if (t < nb) partial[t] = (t == 0) ? 0 : s[t - 1];
}

__global__ void scan3(const int* __restrict__ tmp, const int* __restrict__ partial,
                      int* __restrict__ off, int n) {
  int i = blockIdx.x * blockDim.x + threadIdx.x;
  if (i == 0) off[0] = 0;
  if (i < n) off[i + 1] = tmp[i] + partial[i >> 10];
}

__global__ void scatter_kernel(const int* __restrict__ rows, const int* __restrict__ cols,
                               const int* __restrict__ off_u, const int* __restrict__ off_i,
                               int* __restrict__ cur_u, int* __restrict__ cur_i,
                               int* __restrict__ el_u, int* __restrict__ el_i, int nnz) {
  int e = blockIdx.x * blockDim.x + threadIdx.x;
  if (e >= nnz) return;
  int r = rows[e];
  int p = atomicAdd(&cur_u[r], 1);
  el_u[off_u[r] + p] = e;
  int c = cols[e];
  int q = atomicAdd(&cur_i[c], 1);
  el_i[off_i[c] + q] = e;
}

// ===========================================================================
// Row-wise SpMM (no atomics), fused residual + leaky. One wave per row.
// ===========================================================================
__global__ void spmm_rows(const int* __restrict__ off, const int* __restrict__ elist,
                          const int* __restrict__ gat,
                          const float* __restrict__ vals, const float* __restrict__ dr,
                          const float* __restrict__ Esrc, const float* __restrict__ base,
                          float* __restrict__ out, int n) {
  int wid = threadIdx.x >> 6, lane = threadIdx.x & 63;
  int r = blockIdx.x * 4 + wid;
  if (r >= n) return;
  int i0 = off[r], i1 = off[r + 1];
  float acc = 0.0f;
  int i = i0;
  for (; i + 1 < i1; i += 2) {
    int e0 = elist[i], e1 = elist[i + 1];
    int g0 = gat[e0], g1 = gat[e1];
    float dv0 = (dr[e0] >= DROP_) ? vals[e0] * (1.0f / (1.0f - DROP_)) : 0.0f;
    float dv1 = (dr[e1] >= DROP_) ? vals[e1] * (1.0f / (1.0f - DROP_)) : 0.0f;
    acc += dv0 * Esrc[(size_t)g0 * DD + lane];
    acc += dv1 * Esrc[(size_t)g1 * DD + lane];
  }
  if (i < i1) {
    int e0 = elist[i];
    int g0 = gat[e0];
    float dv0 = (dr[e0] >= DROP_) ? vals[e0] * (1.0f / (1.0f - DROP_)) : 0.0f;
    acc += dv0 * Esrc[(size_t)g0 * DD + lane];
  }
  size_t o = (size_t)r * DD + lane;
  out[o] = base[o] + leaky(acc);
}

// Layer-2 SpMM only for gathered batch rows; compact output [nb][64].
__global__ void spmm_batch(const int* __restrict__ ids,
                           const int* __restrict__ off, const int* __restrict__ elist,
                           const int* __restrict__ gat,
                           const float* __restrict__ vals, const float* __restrict__ dr,
                           const float* __restrict__ Esrc, const float* __restrict__ base,
                           float* __restrict__ out, int nb) {
  int wid = threadIdx.x >> 6, lane = threadIdx.x & 63;
  int i = blockIdx.x * 4 + wid;
  if (i >= nb) return;
  int r = ids[i];
  int i0 = off[r], i1 = off[r + 1];
  float acc = 0.0f;
  for (int j = i0; j < i1; ++j) {
    int e = elist[j];
    int g = gat[e];
    float dv = (dr[e] >= DROP_) ? vals[e] * (1.0f / (1.0f - DROP_)) : 0.0f;
    acc += dv * Esrc[(size_t)g * DD + lane];
  }
  out[(size_t)i * DD + lane] = base[(size_t)r * DD + lane] + leaky(acc);
}

// ===========================================================================
// Dual tall-skinny GEMM: C[64][64] = A[64][N] @ B[N][64], two problems per
// launch (blockIdx.y). Per-block partials, no atomics.
// ===========================================================================
__global__ void gemm_dual(const float* __restrict__ A0, const float* __restrict__ B0,
                          int N0, float* __restrict__ C0,
                          const float* __restrict__ A1, const float* __restrict__ B1,
                          int N1, float* __restrict__ C1) {
  const float* A = blockIdx.y ? A1 : A0;
  const float* B = blockIdx.y ? B1 : B0;
  float* Cp = blockIdx.y ? C1 : C0;
  int N = blockIdx.y ? N1 : N0;
  int d  = threadIdx.x & 63;
  int r0 = (threadIdx.x >> 6) * 16;
  int span = (N + gridDim.x - 1) / gridDim.x;
  int j0 = blockIdx.x * span;
  int j1 = min(j0 + span, N);
  float acc[16];
#pragma unroll
  for (int i = 0; i < 16; ++i) acc[i] = 0.0f;
  int j = j0;
  for (; j + 3 < j1; j += 4) {
    float b0 = B[(size_t)j * DD + d];
    float b1 = B[(size_t)(j + 1) * DD + d];
    float b2 = B[(size_t)(j + 2) * DD + d];
    float b3 = B[(size_t)(j + 3) * DD + d];
#pragma unroll
    for (int i = 0; i < 16; ++i) {
      const float* Ar = A + (size_t)(r0 + i) * N + j;
      acc[i] += Ar[0] * b0 + Ar[1] * b1 + Ar[2] * b2 + Ar[3] * b3;
    }
  }
  for (; j < j1; ++j) {
    float b = B[(size_t)j * DD + d];
#pragma unroll
    for (int i = 0; i < 16; ++i)
      acc[i] += A[(size_t)(r0 + i) * N + j] * b;
  }
#pragma unroll
  for (int i = 0; i < 16; ++i)
    Cp[(size_t)blockIdx.x * 4096 + (r0 + i) * DD + d] = acc[i];
}

__global__ void gemm_reduce_dual(const float* __restrict__ Cp0, float* __restrict__ C0,
                                 const float* __restrict__ Cp1, float* __restrict__ C1) {
  const float* Cp = blockIdx.y ? Cp1 : Cp0;
  float* C = blockIdx.y ? C1 : C0;
  int idx = blockIdx.x * 256 + threadIdx.x;  // 16 x-blocks cover 4096
  float s = 0.0f;
  for (int b = 0; b < GEMM_BLOCKS; ++b) s += Cp[(size_t)b * 4096 + idx];
  C[idx] = s;
}

// ===========================================================================
// h for BOTH views and BOTH layers of one side:
// h = l2norm(leaky(((svd+sign(svd)*l2norm(noise)*EPS)*s)[ids] @ M_l)) @ W_l
// grid (BB/4, LL). hout layout [layer][view][BB][64].
// ===========================================================================
__global__ void h_kernel2(const float* __restrict__ svd,
                          const float* __restrict__ n1, const float* __restrict__ n2,
                          const float* __restrict__ sdiag,
                          const float* __restrict__ Mb,  // [LL][64][64]
                          const float* __restrict__ Wb,  // [LL][64][64]
                          const int*   __restrict__ ids,
                          float*       __restrict__ hout) {
  int layer = blockIdx.y;
  const float* M = Mb + layer * 4096;
  const float* W = Wb + layer * 4096;
  int wid  = threadIdx.x >> 6;
  int lane = threadIdx.x & 63;
  int i = blockIdx.x * 4 + wid;
  int id = ids[i];
  float sv = svd[(size_t)id * DD + lane];
  float sgn = (sv > 0.0f) ? 1.0f : ((sv < 0.0f) ? -1.0f : 0.0f);
  float sd = sdiag[lane];

  float z1 = n1[(size_t)id * DD + lane];
  float z2 = n2[(size_t)id * DD + lane];
  float d1 = fmaxf(sqrtf(waveReduceSum(z1 * z1)), 1e-12f);
  float d2 = fmaxf(sqrtf(waveReduceSum(z2 * z2)), 1e-12f);
  float g1 = (sv + sgn * (z1 / d1) * EPS_) * sd;
  float g2 = (sv + sgn * (z2 / d2) * EPS_) * sd;

  float a1 = 0.0f, a2 = 0.0f;
#pragma unroll
  for (int k = 0; k < 64; ++k) {
    float m = M[k * DD + lane];
    a1 += __shfl(g1, k, 64) * m;
    a2 += __shfl(g2, k, 64) * m;
  }
  a1 = leaky(a1); a2 = leaky(a2);
  float s1 = fmaxf(sqrtf(waveReduceSum(a1 * a1)), 1e-12f);
  float s2 = fmaxf(sqrtf(waveReduceSum(a2 * a2)), 1e-12f);
  float gn1 = a1 / s1, gn2 = a2 / s2;

  float h1 = 0.0f, h2 = 0.0f;
#pragma unroll
  for (int k = 0; k < 64; ++k) {
    float w = W[k * DD + lane];
    h1 += __shfl(gn1, k, 64) * w;
    h2 += __shfl(gn2, k, 64) * w;
  }
  size_t b0 = ((size_t)(layer * 2 + 0) * BB + i) * DD + lane;
  size_t b1 = ((size_t)(layer * 2 + 1) * BB + i) * DD + lane;
  hout[b0] = h1;
  hout[b1] = h2;
}

// ===========================================================================
// score tiles: all 4 (layer,side) at once via blockIdx.z.
// Block (bx,by,z): 64x64 tile of S = h1 @ h2^T, exp, row-sum ->
// negpart[z][by][i0+row] (non-atomic).
// ===========================================================================
__global__ void score_tiles(const float* __restrict__ hu, const float* __restrict__ hv,
                            float* __restrict__ negpart) {
  __shared__ float s1[64][65];
  __shared__ float s2[64][65];
  int z = blockIdx.z;
  int layer = z >> 1, side = z & 1;
  const float* hb = side ? hv : hu;
  const float* h1 = hb + (size_t)(layer * 2 + 0) * BB * DD;
  const float* h2 = hb + (size_t)(layer * 2 + 1) * BB * DD;
  int i0 = blockIdx.x * 64, j0 = blockIdx.y * 64;
  int t = threadIdx.x;
#pragma unroll
  for (int k = 0; k < 16; ++k) {
    int lin = t + k * 256;
    int r = lin >> 6, c = lin & 63;
    s1[r][c] = h1[(size_t)(i0 + r) * DD + c];
    s2[r][c] = h2[(size_t)(j0 + r) * DD + c];
  }
  __syncthreads();
  int ti = t >> 4, tj = t & 15;
  float acc[4][4];
#pragma unroll
  for (int x = 0; x < 4; ++x)
#pragma unroll
    for (int y = 0; y < 4; ++y) acc[x][y] = 0.0f;
  for (int d = 0; d < 64; ++d) {
    float a[4], b[4];
#pragma unroll
    for (int k = 0; k < 4; ++k) { a[k] = s1[ti * 4 + k][d]; b[k] = s2[tj * 4 + k][d]; }
#pragma unroll
    for (int x = 0; x < 4; ++x)
#pragma unroll
      for (int y = 0; y < 4; ++y) acc[x][y] += a[x] * b[y];
  }
  float rsum[4];
#pragma unroll
  for (int x = 0; x < 4; ++x) {
    float s = 0.0f;
#pragma unroll
    for (int y = 0; y < 4; ++y) s += expf(acc[x][y] * (1.0f / TEMP_));
    rsum[x] = s;
  }
  __syncthreads();  // reuse s1 for the 16-way row reduction
#pragma unroll
  for (int x = 0; x < 4; ++x) s1[ti * 4 + x][tj] = rsum[x];
  __syncthreads();
  if (t < 64) {
    float s = 0.0f;
#pragma unroll
    for (int c = 0; c < 16; ++c) s += s1[t][c];
    negpart[((size_t)z * 32 + blockIdx.y) * BB + i0 + t] = s;
  }
}

// loss fold: thread-per-row; block reduce; one atomic per block.
__global__ void score_loss(const float* __restrict__ hu, const float* __restrict__ hv,
                           const float* __restrict__ negpart,
                           const float* __restrict__ u_mask, const float* __restrict__ i_mask,
                           float* __restrict__ loss_acc) {
  __shared__ float red[256];
  int z = blockIdx.y;
  int layer = z >> 1, side = z & 1;
  const float* hb = side ? hv : hu;
  const float* h1 = hb + (size_t)(layer * 2 + 0) * BB * DD;
  const float* h2 = hb + (size_t)(layer * 2 + 1) * BB * DD;
  const float* mask = (side ? i_mask : u_mask) + layer * BB;
  int i = blockIdx.x * 256 + threadIdx.x;
  const float4* a = (const float4*)(h1 + (size_t)i * DD);
  const float4* b = (const float4*)(h2 + (size_t)i * DD);
  float pos = 0.0f;
#pragma unroll
  for (int k = 0; k < 16; ++k) {
    float4 av = a[k], bv = b[k];
    pos += av.x * bv.x + av.y * bv.y + av.z * bv.z + av.w * bv.w;
  }
  float ng = 0.0f;
  for (int jt = 0; jt < 32; ++jt) ng += negpart[((size_t)z * 32 + jt) * BB + i];
  float ps = expf(pos * (1.0f / TEMP_));
  float m = (mask[i] > 0.5f) ? 1.0f : 0.0f;
  float li = -logf(ps / (ng + 1e-8f) + 1e-8f) * m;
  red[threadIdx.x] = li;
  __syncthreads();
  for (int ofs = 128; ofs >= 1; ofs >>= 1) {
    if (threadIdx.x < ofs) red[threadIdx.x] += red[threadIdx.x + ofs];
    __syncthreads();
  }
  if (threadIdx.x == 0) unsafeAtomicAdd(loss_acc, red[0]);
}

// ===========================================================================
// BPR: thread-per-row, float4, block reduce, one atomic per block.
// ===========================================================================
__global__ void bpr_kernel(const float* __restrict__ Eu0, const float* __restrict__ EU1,
                           const float* __restrict__ bu,
                           const float* __restrict__ Ei0, const float* __restrict__ EI1,
                           const float* __restrict__ bpos, const float* __restrict__ bneg,
                           const int* __restrict__ uids, const int* __restrict__ pos,
                           const int* __restrict__ neg,
                           float* __restrict__ acc_r) {
  __shared__ float red[256];
  int i = blockIdx.x * 256 + threadIdx.x;
  const float4* u0 = (const float4*)(Eu0 + (size_t)uids[i] * DD);
  const float4* u1 = (const float4*)(EU1 + (size_t)uids[i] * DD);
  const float4* u2 = (const float4*)(bu  + (size_t)i * DD);
  const float4* p0 = (const float4*)(Ei0 + (size_t)pos[i] * DD);
  const float4* p1 = (const float4*)(EI1 + (size_t)pos[i] * DD);
  const float4* p2 = (const float4*)(bpos + (size_t)i * DD);
  const float4* n0 = (const float4*)(Ei0 + (size_t)neg[i] * DD);
  const float4* n1 = (const float4*)(EI1 + (size_t)neg[i] * DD);
  const float4* n2 = (const float4*)(bneg + (size_t)i * DD);
  float ps = 0.0f, ns = 0.0f;
#pragma unroll
  for (int k = 0; k < 16; ++k) {
    float4 ua = u0[k], ub = u1[k], uc = u2[k];
    float4 pa = p0[k], pb = p1[k], pc = p2[k];
    float4 na = n0[k], nb = n1[k], nc = n2[k];
    float ux = ua.x + ub.x + uc.x, uy = ua.y + ub.y + uc.y,
          uz = ua.z + ub.z + uc.z, uw = ua.w + ub.w + uc.w;
    ps += ux * (pa.x + pb.x + pc.x) + uy * (pa.y + pb.y + pc.y)
        + uz * (pa.z + pb.z + pc.z) + uw * (pa.w + pb.w + pc.w);
    ns += ux * (na.x + nb.x + nc.x) + uy * (na.y + nb.y + nc.y)
        + uz * (na.z + nb.z + nc.z) + uw * (na.w + nb.w + nc.w);
  }
  red[threadIdx.x] = fmaxf(1.0f - ps + ns, 0.0f);
  __syncthreads();
  for (int ofs = 128; ofs >= 1; ofs >>= 1) {
    if (threadIdx.x < ofs) red[threadIdx.x] += red[threadIdx.x + ofs];
    __syncthreads();
  }
  if (threadIdx.x == 0) unsafeAtomicAdd(acc_r, red[0]);
}

__global__ void finalize_kernel(const float* __restrict__ acc, float* __restrict__ out) {
  float lr = acc[0] / (float)BB;
  float ls = acc[1];
  out[0] = lr + LAM1 * ls;
  out[1] = lr;
  out[2] = ls;
}

// ===========================================================================
extern "C" void kernel_launch(void* const* d_in, const int* in_sizes, int n_in,
                              void* d_out, int out_size, void* d_ws, size_t ws_size,
                              hipStream_t stream) {
  const float* E_u_0   = (const float*)d_in[0];
  const float* E_i_0   = (const float*)d_in[1];
  const float* svd_u   = (const float*)d_in[2];
  const float* svd_v   = (const float*)d_in[3];
  const float* sdiag   = (const float*)d_in[4];
  const float* ut      = (const float*)d_in[5];
  const float* vt      = (const float*)d_in[6];
  const float* W_u     = (const float*)d_in[7];
  const float* W_i     = (const float*)d_in[8];
  const float* adjv    = (const float*)d_in[9];
  const float* dropr   = (const float*)d_in[10];
  const float* noise_u1= (const float*)d_in[11];
  const float* noise_v1= (const float*)d_in[12];
  const float* noise_u2= (const float*)d_in[13];
  const float* noise_v2= (const float*)d_in[14];
  const float* u_mask  = (const float*)d_in[15];
  const float* i_mask  = (const float*)d_in[16];
  const int*   rows    = (const int*)d_in[17];
  const int*   cols    = (const int*)d_in[18];
  const int*   uids    = (const int*)d_in[19];
  const int*   iids    = (const int*)d_in[20];
  const int*   pos     = (const int*)d_in[21];
  const int*   neg     = (const int*)d_in[22];
  float* out = (float*)d_out;

  // ---- workspace layout ----
  float* ws    = (float*)d_ws;
  float* EU1   = ws;                           // 6,400,000
  float* EI1   = EU1 + (size_t)N_U * DD;       // 3,200,000
  float* bu    = EI1 + (size_t)N_I * DD;       // 131072
  float* bpos  = bu   + (size_t)BB * DD;       // 131072
  float* bneg  = bpos + (size_t)BB * DD;       // 131072
  float* hu    = bneg + (size_t)BB * DD;       // [2][2][BB][64] = 524288
  float* hv    = hu   + (size_t)4 * BB * DD;   // 524288
  float* negp  = hv   + (size_t)4 * BB * DD;   // [4][32][BB] = 262144
  float* CpA   = negp + (size_t)4 * 32 * BB;   // 512*4096 = 2,097,152
  float* CpB   = CpA  + (size_t)GEMM_BLOCKS * 4096; // 2,097,152
  float* vtei  = CpB  + (size_t)GEMM_BLOCKS * 4096; // 2*4096
  float* uteu  = vtei + 2 * DD * DD;           // 2*4096
  float* accs  = uteu + 2 * DD * DD;           // 16
  int* ip      = (int*)(accs + 16);
  int* el_u    = ip;                           // NNZ
  int* el_i    = el_u + NNZ_;                  // NNZ
  int* off_u   = el_i + NNZ_;                  // N_U+1
  int* off_i   = off_u + (N_U + 1);            // N_I+1
  int* deg_u   = off_i + (N_I + 1);            // N_U
  int* deg_i   = deg_u + N_U;                  // N_I
  int* cur_u   = deg_i + N_I;                  // N_U
  int* cur_i   = cur_u + N_U;                  // N_I
  int* stmp    = cur_i + N_I;                  // N_U
  int* spart   = stmp + N_U;                   // 256

  const int TB = 256;
  dim3 blk(TB);
  int eg = (NNZ_ + TB - 1) / TB;
  int row_grid = BB / 4;

  hipMemsetAsync(deg_u, 0, (size_t)(2 * N_U + 2 * N_I) * sizeof(int), stream);
  hipMemsetAsync(accs, 0, 16 * sizeof(float), stream);

  // ---- CSR build ----
  hist_kernel<<<eg, blk, 0, stream>>>(rows, cols, deg_u, deg_i, NNZ_);
  {
    int nb_u = (N_U + 1023) / 1024, nb_i = (N_I + 1023) / 1024;
    scan1<<<nb_u, blk, 0, stream>>>(deg_u, stmp, spart, N_U);
    scan2<<<1, blk, 0, stream>>>(spart, nb_u);
    scan3<<<(N_U + TB - 1) / TB, blk, 0, stream>>>(stmp, spart, off_u, N_U);
    scan1<<<nb_i, blk, 0, stream>>>(deg_i, stmp, spart, N_I);
    scan2<<<1, blk, 0, stream>>>(spart, nb_i);
    scan3<<<(N_I + TB - 1) / TB, blk, 0, stream>>>(stmp, spart, off_i, N_I);
  }
  scatter_kernel<<<eg, blk, 0, stream>>>(rows, cols, off_u, off_i, cur_u, cur_i,
                                         el_u, el_i, NNZ_);

  // ---- layer-1 small GEMMs (dual, partials, reduce) ----
  gemm_dual<<<dim3(GEMM_BLOCKS, 2), blk, 0, stream>>>(vt, E_i_0, N_I, CpA,
                                                      ut, E_u_0, N_U, CpB);
  gemm_reduce_dual<<<dim3(16, 2), blk, 0, stream>>>(CpA, vtei, CpB, uteu);

  // ---- layer-1 full SpMM (fused residual+leaky) ----
  spmm_rows<<<(N_U + 3) / 4, blk, 0, stream>>>(off_u, el_u, cols, adjv,
      dropr + 0 * (size_t)NNZ_, E_i_0, E_u_0, EU1, N_U);
  spmm_rows<<<(N_I + 3) / 4, blk, 0, stream>>>(off_i, el_i, rows, adjv,
      dropr + 1 * (size_t)NNZ_, E_u_0, E_i_0, EI1, N_I);

  // ---- layer-2 small GEMMs ----
  gemm_dual<<<dim3(GEMM_BLOCKS, 2), blk, 0, stream>>>(vt, EI1, N_I, CpA,
                                                      ut, EU1, N_U, CpB);
  gemm_reduce_dual<<<dim3(16, 2), blk, 0, stream>>>(CpA, vtei + 4096, CpB, uteu + 4096);

  // ---- layer-2 SpMM only at batch rows ----
  spmm_batch<<<row_grid, blk, 0, stream>>>(uids, off_u, el_u, cols, adjv,
      dropr + 2 * (size_t)NNZ_, EI1, EU1, bu, BB);
  spmm_batch<<<row_grid, blk, 0, stream>>>(pos, off_i, el_i, rows, adjv,
      dropr + 3 * (size_t)NNZ_, EU1, EI1, bpos, BB);
  spmm_batch<<<row_grid, blk, 0, stream>>>(neg, off_i, el_i, rows, adjv,
      dropr + 3 * (size_t)NNZ_, EU1, EI1, bneg, BB);

  // ---- contrastive: h (both layers+views per side), tiles, loss ----
  h_kernel2<<<dim3(row_grid, LL), blk, 0, stream>>>(svd_u, noise_u1, noise_u2, sdiag,
                                                    vtei, W_u, uids, hu);
  h_kernel2<<<dim3(row_grid, LL), blk, 0, stream>>>(svd_v, noise_v1, noise_v2, sdiag,
                                                    uteu, W_i, iids, hv);
  score_tiles<<<dim3(32, 32, 4), blk, 0, stream>>>(hu, hv, negp);
  score_loss<<<dim3(8, 4), blk, 0, stream>>>(hu, hv, negp, u_mask, i_mask, accs + 1);

  // ---- BPR ----
  bpr_kernel<<<8, blk, 0, stream>>>(E_u_0, EU1, bu, E_i_0, EI1, bpos, bneg,
                                    uids, pos, neg, accs);

  finalize_kernel<<<1, 1, 0, stream>>>(accs, out);
}

// Round 4
// 1051.284 us; speedup vs baseline: 4.4619x; 1.1671x over previous
//
#include <hip/hip_runtime.h>
#include <cstddef>

// ---- problem constants (from reference) ----
#define N_U   100000
#define N_I   50000
#define DD    64
#define NNZ_  1000000
#define LL    2
#define TEMP_ 0.2f
#define LAM1  0.2f
#define DROP_ 0.1f
#define EPS_  0.05f
#define BB    2048
#define GEMM_BLOCKS 256

__device__ __forceinline__ float leaky(float x) { return x >= 0.0f ? x : 0.5f * x; }

__device__ __forceinline__ float waveReduceSum(float v) {
#pragma unroll
  for (int m = 32; m >= 1; m >>= 1) v += __shfl_xor(v, m, 64);
  return v;
}

// wave-uniform lane broadcast (loop index is uniform -> v_readlane, 1 inst)
__device__ __forceinline__ int rlanei(int v, int l) {
  return __builtin_amdgcn_readlane(v, l);
}
__device__ __forceinline__ float rlanef(float v, int l) {
  return __int_as_float(__builtin_amdgcn_readlane(__float_as_int(v), l));
}

// ===========================================================================
// CSR build: histogram -> scan (3-phase) -> scatter (+ edge payload build)
// ===========================================================================
__global__ void hist_kernel(const int* __restrict__ rows, const int* __restrict__ cols,
                            int* __restrict__ deg_u, int* __restrict__ deg_i, int nnz) {
  int e = blockIdx.x * blockDim.x + threadIdx.x;
  if (e >= nnz) return;
  atomicAdd(&deg_u[rows[e]], 1);
  atomicAdd(&deg_i[cols[e]], 1);
}

__global__ void scan1(const int* __restrict__ in, int* __restrict__ tmp,
                      int* __restrict__ partial, int n) {
  __shared__ int s[256];
  int t = threadIdx.x;
  int base = blockIdx.x * 1024;
  int v[4]; int tsum = 0;
#pragma unroll
  for (int k = 0; k < 4; ++k) {
    int idx = base + t * 4 + k;
    v[k] = (idx < n) ? in[idx] : 0;
    tsum += v[k];
  }
  s[t] = tsum;
  __syncthreads();
  for (int ofs = 1; ofs < 256; ofs <<= 1) {
    int x = (t >= ofs) ? s[t - ofs] : 0;
    __syncthreads();
    s[t] += x;
    __syncthreads();
  }
  if (t == 255) partial[blockIdx.x] = s[255];
  int run = (t == 0) ? 0 : s[t - 1];
#pragma unroll
  for (int k = 0; k < 4; ++k) {
    run += v[k];
    int idx = base + t * 4 + k;
    if (idx < n) tmp[idx] = run;
  }
}

__global__ void scan2(int* __restrict__ partial, int nb) {
  __shared__ int s[256];
  int t = threadIdx.x;
  s[t] = (t < nb) ? partial[t] : 0;
  __syncthreads();
  for (int ofs = 1; ofs < 256; ofs <<= 1) {
    int x = (t >= ofs) ? s[t - ofs] : 0;
    __syncthreads();
    s[t] += x;
    __syncthreads();
  }
  if (t < nb) partial[t] = (t == 0) ? 0 : s[t - 1];
}

__global__ void scan3(const int* __restrict__ tmp, const int* __restrict__ partial,
                      int* __restrict__ off, int n) {
  int i = blockIdx.x * blockDim.x + threadIdx.x;
  if (i == 0) off[0] = 0;
  if (i < n) off[i + 1] = tmp[i] + partial[i >> 10];
}

// Scatter to CSR position AND build per-edge payloads for all (layer,dir):
// sequential reads of rows/cols/vals/dr*, scattered 4B writes (cache-absorbed).
__global__ void scatter_build(const int* __restrict__ rows, const int* __restrict__ cols,
                              const float* __restrict__ vals, const float* __restrict__ dropr,
                              const int* __restrict__ off_u, const int* __restrict__ off_i,
                              int* __restrict__ cur_u, int* __restrict__ cur_i,
                              int* __restrict__ gat_u, int* __restrict__ gat_i,
                              float* __restrict__ dvu1, float* __restrict__ dvu2,
                              float* __restrict__ dvi1, float* __restrict__ dvi2,
                              int nnz) {
  int e = blockIdx.x * blockDim.x + threadIdx.x;
  if (e >= nnz) return;
  int r = rows[e], c = cols[e];
  float v = vals[e] * (1.0f / (1.0f - DROP_));
  float k0 = (dropr[e] >= DROP_) ? v : 0.0f;                          // L1 user-dir
  float k1 = (dropr[(size_t)NNZ_ + e] >= DROP_) ? v : 0.0f;           // L1 item-dir
  float k2 = (dropr[(size_t)2 * NNZ_ + e] >= DROP_) ? v : 0.0f;       // L2 user-dir
  float k3 = (dropr[(size_t)3 * NNZ_ + e] >= DROP_) ? v : 0.0f;       // L2 item-dir
  int p = off_u[r] + atomicAdd(&cur_u[r], 1);
  gat_u[p] = c; dvu1[p] = k0; dvu2[p] = k2;
  int q = off_i[c] + atomicAdd(&cur_i[c], 1);
  gat_i[q] = r; dvi1[q] = k1; dvi2[q] = k3;
}

// ===========================================================================
// Layer-1 SpMM, both sides in one launch. One wave per row; lane = dim.
// Metadata preloaded coalesced per 64-edge chunk, broadcast via readlane.
//   out[r] = base[r] + leaky( sum_e dv[e] * Esrc[gat[e]] )
// ===========================================================================
__global__ void spmm_all(const int* __restrict__ off_u, const int* __restrict__ gat_u,
                         const float* __restrict__ dvu,
                         const int* __restrict__ off_i, const int* __restrict__ gat_i,
                         const float* __restrict__ dvi,
                         const float* __restrict__ Eu0, const float* __restrict__ Ei0,
                         float* __restrict__ EU1, float* __restrict__ EI1) {
  int wid = threadIdx.x >> 6, lane = threadIdx.x & 63;
  int r = blockIdx.x * 4 + wid;
  const int* off; const int* gat; const float* dv;
  const float* Esrc; const float* base; float* out;
  if (r < N_U) {
    off = off_u; gat = gat_u; dv = dvu; Esrc = Ei0; base = Eu0; out = EU1;
  } else {
    r -= N_U;
    if (r >= N_I) return;
    off = off_i; gat = gat_i; dv = dvi; Esrc = Eu0; base = Ei0; out = EI1;
  }
  int i0 = off[r], i1 = off[r + 1];
  float acc = 0.0f;
  for (int p = i0; p < i1; p += 64) {
    int cn = min(64, i1 - p);
    float dvl = 0.0f; int gl = 0;
    if (lane < cn) { dvl = dv[p + lane]; gl = gat[p + lane]; }
    int j = 0;
    for (; j + 3 < cn; j += 4) {
      float d0 = rlanef(dvl, j), d1 = rlanef(dvl, j + 1),
            d2 = rlanef(dvl, j + 2), d3 = rlanef(dvl, j + 3);
      int g0 = rlanei(gl, j), g1 = rlanei(gl, j + 1),
          g2 = rlanei(gl, j + 2), g3 = rlanei(gl, j + 3);
      float e0 = Esrc[(size_t)g0 * DD + lane];
      float e1 = Esrc[(size_t)g1 * DD + lane];
      float e2 = Esrc[(size_t)g2 * DD + lane];
      float e3 = Esrc[(size_t)g3 * DD + lane];
      acc += d0 * e0; acc += d1 * e1; acc += d2 * e2; acc += d3 * e3;
    }
    for (; j < cn; ++j)
      acc += rlanef(dvl, j) * Esrc[(size_t)rlanei(gl, j) * DD + lane];
  }
  size_t o = (size_t)r * DD + lane;
  out[o] = base[o] + leaky(acc);
}

// Layer-2 SpMM only at gathered batch rows (uids | pos | neg via blockIdx.y).
__global__ void spmm_batch3(const int* __restrict__ uids, const int* __restrict__ pos,
                            const int* __restrict__ neg,
                            const int* __restrict__ off_u, const int* __restrict__ gat_u,
                            const float* __restrict__ dvu2,
                            const int* __restrict__ off_i, const int* __restrict__ gat_i,
                            const float* __restrict__ dvi2,
                            const float* __restrict__ EU1, const float* __restrict__ EI1,
                            float* __restrict__ bu, float* __restrict__ bpos,
                            float* __restrict__ bneg) {
  int z = blockIdx.y;
  const int* ids = (z == 0) ? uids : ((z == 1) ? pos : neg);
  const int* off = (z == 0) ? off_u : off_i;
  const int* gat = (z == 0) ? gat_u : gat_i;
  const float* dv = (z == 0) ? dvu2 : dvi2;
  const float* Esrc = (z == 0) ? EI1 : EU1;
  const float* base = (z == 0) ? EU1 : EI1;
  float* out = (z == 0) ? bu : ((z == 1) ? bpos : bneg);
  int wid = threadIdx.x >> 6, lane = threadIdx.x & 63;
  int i = blockIdx.x * 4 + wid;
  int r = ids[i];
  int i0 = off[r], i1 = off[r + 1];
  float acc = 0.0f;
  for (int p = i0; p < i1; p += 64) {
    int cn = min(64, i1 - p);
    float dvl = 0.0f; int gl = 0;
    if (lane < cn) { dvl = dv[p + lane]; gl = gat[p + lane]; }
    int j = 0;
    for (; j + 3 < cn; j += 4) {
      float d0 = rlanef(dvl, j), d1 = rlanef(dvl, j + 1),
            d2 = rlanef(dvl, j + 2), d3 = rlanef(dvl, j + 3);
      int g0 = rlanei(gl, j), g1 = rlanei(gl, j + 1),
          g2 = rlanei(gl, j + 2), g3 = rlanei(gl, j + 3);
      acc += d0 * Esrc[(size_t)g0 * DD + lane];
      acc += d1 * Esrc[(size_t)g1 * DD + lane];
      acc += d2 * Esrc[(size_t)g2 * DD + lane];
      acc += d3 * Esrc[(size_t)g3 * DD + lane];
    }
    for (; j < cn; ++j)
      acc += rlanef(dvl, j) * Esrc[(size_t)rlanei(gl, j) * DD + lane];
  }
  out[(size_t)i * DD + lane] = base[(size_t)r * DD + lane] + leaky(acc);
}

// ===========================================================================
// Dual tall-skinny GEMM: C[64][64] = A[64][N] @ B[N][64]; per-block partials.
// ===========================================================================
__global__ void gemm_dual(const float* __restrict__ A0, const float* __restrict__ B0,
                          int N0, float* __restrict__ C0,
                          const float* __restrict__ A1, const float* __restrict__ B1,
                          int N1, float* __restrict__ C1) {
  const float* A = blockIdx.y ? A1 : A0;
  const float* B = blockIdx.y ? B1 : B0;
  float* Cp = blockIdx.y ? C1 : C0;
  int N = blockIdx.y ? N1 : N0;
  int d  = threadIdx.x & 63;
  int r0 = (threadIdx.x >> 6) * 16;
  int span = (N + gridDim.x - 1) / gridDim.x;
  int j0 = blockIdx.x * span;
  int j1 = min(j0 + span, N);
  float acc[16];
#pragma unroll
  for (int i = 0; i < 16; ++i) acc[i] = 0.0f;
  int j = j0;
  for (; j + 3 < j1; j += 4) {
    float b0 = B[(size_t)j * DD + d];
    float b1 = B[(size_t)(j + 1) * DD + d];
    float b2 = B[(size_t)(j + 2) * DD + d];
    float b3 = B[(size_t)(j + 3) * DD + d];
#pragma unroll
    for (int i = 0; i < 16; ++i) {
      const float* Ar = A + (size_t)(r0 + i) * N + j;
      acc[i] += Ar[0] * b0 + Ar[1] * b1 + Ar[2] * b2 + Ar[3] * b3;
    }
  }
  for (; j < j1; ++j) {
    float b = B[(size_t)j * DD + d];
#pragma unroll
    for (int i = 0; i < 16; ++i)
      acc[i] += A[(size_t)(r0 + i) * N + j] * b;
  }
#pragma unroll
  for (int i = 0; i < 16; ++i)
    Cp[(size_t)blockIdx.x * 4096 + (r0 + i) * DD + d] = acc[i];
}

__global__ void gemm_reduce_dual(const float* __restrict__ Cp0, float* __restrict__ C0,
                                 const float* __restrict__ Cp1, float* __restrict__ C1) {
  const float* Cp = blockIdx.y ? Cp1 : Cp0;
  float* C = blockIdx.y ? C1 : C0;
  int idx = blockIdx.x * 256 + threadIdx.x;
  float s = 0.0f;
  for (int b = 0; b < GEMM_BLOCKS; ++b) s += Cp[(size_t)b * 4096 + idx];
  C[idx] = s;
}

// ===========================================================================
// h for both views and both layers of one side. hout [layer][view][BB][64].
// ===========================================================================
__global__ void h_kernel2(const float* __restrict__ svd,
                          const float* __restrict__ n1, const float* __restrict__ n2,
                          const float* __restrict__ sdiag,
                          const float* __restrict__ Mb,
                          const float* __restrict__ Wb,
                          const int*   __restrict__ ids,
                          float*       __restrict__ hout) {
  int layer = blockIdx.y;
  const float* M = Mb + layer * 4096;
  const float* W = Wb + layer * 4096;
  int wid  = threadIdx.x >> 6;
  int lane = threadIdx.x & 63;
  int i = blockIdx.x * 4 + wid;
  int id = ids[i];
  float sv = svd[(size_t)id * DD + lane];
  float sgn = (sv > 0.0f) ? 1.0f : ((sv < 0.0f) ? -1.0f : 0.0f);
  float sd = sdiag[lane];

  float z1 = n1[(size_t)id * DD + lane];
  float z2 = n2[(size_t)id * DD + lane];
  float d1 = fmaxf(sqrtf(waveReduceSum(z1 * z1)), 1e-12f);
  float d2 = fmaxf(sqrtf(waveReduceSum(z2 * z2)), 1e-12f);
  float g1 = (sv + sgn * (z1 / d1) * EPS_) * sd;
  float g2 = (sv + sgn * (z2 / d2) * EPS_) * sd;

  float a1 = 0.0f, a2 = 0.0f;
#pragma unroll
  for (int k = 0; k < 64; ++k) {
    float m = M[k * DD + lane];
    a1 += rlanef(g1, k) * m;
    a2 += rlanef(g2, k) * m;
  }
  a1 = leaky(a1); a2 = leaky(a2);
  float s1 = fmaxf(sqrtf(waveReduceSum(a1 * a1)), 1e-12f);
  float s2 = fmaxf(sqrtf(waveReduceSum(a2 * a2)), 1e-12f);
  float gn1 = a1 / s1, gn2 = a2 / s2;

  float h1 = 0.0f, h2 = 0.0f;
#pragma unroll
  for (int k = 0; k < 64; ++k) {
    float w = W[k * DD + lane];
    h1 += rlanef(gn1, k) * w;
    h2 += rlanef(gn2, k) * w;
  }
  size_t b0 = ((size_t)(layer * 2 + 0) * BB + i) * DD + lane;
  size_t b1 = ((size_t)(layer * 2 + 1) * BB + i) * DD + lane;
  hout[b0] = h1;
  hout[b1] = h2;
}

// ===========================================================================
// score tiles: 64x64 tile of exp(S/T), row-sum partials (non-atomic)
// ===========================================================================
__global__ void score_tiles(const float* __restrict__ hu, const float* __restrict__ hv,
                            float* __restrict__ negpart) {
  __shared__ float s1[64][65];
  __shared__ float s2[64][65];
  int z = blockIdx.z;
  int layer = z >> 1, side = z & 1;
  const float* hb = side ? hv : hu;
  const float* h1 = hb + (size_t)(layer * 2 + 0) * BB * DD;
  const float* h2 = hb + (size_t)(layer * 2 + 1) * BB * DD;
  int i0 = blockIdx.x * 64, j0 = blockIdx.y * 64;
  int t = threadIdx.x;
#pragma unroll
  for (int k = 0; k < 16; ++k) {
    int lin = t + k * 256;
    int r = lin >> 6, c = lin & 63;
    s1[r][c] = h1[(size_t)(i0 + r) * DD + c];
    s2[r][c] = h2[(size_t)(j0 + r) * DD + c];
  }
  __syncthreads();
  int ti = t >> 4, tj = t & 15;
  float acc[4][4];
#pragma unroll
  for (int x = 0; x < 4; ++x)
#pragma unroll
    for (int y = 0; y < 4; ++y) acc[x][y] = 0.0f;
  for (int d = 0; d < 64; ++d) {
    float a[4], b[4];
#pragma unroll
    for (int k = 0; k < 4; ++k) { a[k] = s1[ti * 4 + k][d]; b[k] = s2[tj * 4 + k][d]; }
#pragma unroll
    for (int x = 0; x < 4; ++x)
#pragma unroll
      for (int y = 0; y < 4; ++y) acc[x][y] += a[x] * b[y];
  }
  float rsum[4];
#pragma unroll
  for (int x = 0; x < 4; ++x) {
    float s = 0.0f;
#pragma unroll
    for (int y = 0; y < 4; ++y) s += expf(acc[x][y] * (1.0f / TEMP_));
    rsum[x] = s;
  }
  __syncthreads();
#pragma unroll
  for (int x = 0; x < 4; ++x) s1[ti * 4 + x][tj] = rsum[x];
  __syncthreads();
  if (t < 64) {
    float s = 0.0f;
#pragma unroll
    for (int c = 0; c < 16; ++c) s += s1[t][c];
    negpart[((size_t)z * 32 + blockIdx.y) * BB + i0 + t] = s;
  }
}

__global__ void score_loss(const float* __restrict__ hu, const float* __restrict__ hv,
                           const float* __restrict__ negpart,
                           const float* __restrict__ u_mask, const float* __restrict__ i_mask,
                           float* __restrict__ loss_acc) {
  __shared__ float red[256];
  int z = blockIdx.y;
  int layer = z >> 1, side = z & 1;
  const float* hb = side ? hv : hu;
  const float* h1 = hb + (size_t)(layer * 2 + 0) * BB * DD;
  const float* h2 = hb + (size_t)(layer * 2 + 1) * BB * DD;
  const float* mask = (side ? i_mask : u_mask) + layer * BB;
  int i = blockIdx.x * 256 + threadIdx.x;
  const float4* a = (const float4*)(h1 + (size_t)i * DD);
  const float4* b = (const float4*)(h2 + (size_t)i * DD);
  float pos = 0.0f;
#pragma unroll
  for (int k = 0; k < 16; ++k) {
    float4 av = a[k], bv = b[k];
    pos += av.x * bv.x + av.y * bv.y + av.z * bv.z + av.w * bv.w;
  }
  float ng = 0.0f;
  for (int jt = 0; jt < 32; ++jt) ng += negpart[((size_t)z * 32 + jt) * BB + i];
  float ps = expf(pos * (1.0f / TEMP_));
  float m = (mask[i] > 0.5f) ? 1.0f : 0.0f;
  float li = -logf(ps / (ng + 1e-8f) + 1e-8f) * m;
  red[threadIdx.x] = li;
  __syncthreads();
  for (int ofs = 128; ofs >= 1; ofs >>= 1) {
    if (threadIdx.x < ofs) red[threadIdx.x] += red[threadIdx.x + ofs];
    __syncthreads();
  }
  if (threadIdx.x == 0) unsafeAtomicAdd(loss_acc, red[0]);
}

// ===========================================================================
// BPR
// ===========================================================================
__global__ void bpr_kernel(const float* __restrict__ Eu0, const float* __restrict__ EU1,
                           const float* __restrict__ bu,
                           const float* __restrict__ Ei0, const float* __restrict__ EI1,
                           const float* __restrict__ bpos, const float* __restrict__ bneg,
                           const int* __restrict__ uids, const int* __restrict__ pos,
                           const int* __restrict__ neg,
                           float* __restrict__ acc_r) {
  __shared__ float red[256];
  int i = blockIdx.x * 256 + threadIdx.x;
  const float4* u0 = (const float4*)(Eu0 + (size_t)uids[i] * DD);
  const float4* u1 = (const float4*)(EU1 + (size_t)uids[i] * DD);
  const float4* u2 = (const float4*)(bu  + (size_t)i * DD);
  const float4* p0 = (const float4*)(Ei0 + (size_t)pos[i] * DD);
  const float4* p1 = (const float4*)(EI1 + (size_t)pos[i] * DD);
  const float4* p2 = (const float4*)(bpos + (size_t)i * DD);
  const float4* n0 = (const float4*)(Ei0 + (size_t)neg[i] * DD);
  const float4* n1 = (const float4*)(EI1 + (size_t)neg[i] * DD);
  const float4* n2 = (const float4*)(bneg + (size_t)i * DD);
  float ps = 0.0f, ns = 0.0f;
#pragma unroll
  for (int k = 0; k < 16; ++k) {
    float4 ua = u0[k], ub = u1[k], uc = u2[k];
    float4 pa = p0[k], pb = p1[k], pc = p2[k];
    float4 na = n0[k], nb = n1[k], nc = n2[k];
    float ux = ua.x + ub.x + uc.x, uy = ua.y + ub.y + uc.y,
          uz = ua.z + ub.z + uc.z, uw = ua.w + ub.w + uc.w;
    ps += ux * (pa.x + pb.x + pc.x) + uy * (pa.y + pb.y + pc.y)
        + uz * (pa.z + pb.z + pc.z) + uw * (pa.w + pb.w + pc.w);
    ns += ux * (na.x + nb.x + nc.x) + uy * (na.y + nb.y + nc.y)
        + uz * (na.z + nb.z + nc.z) + uw * (na.w + nb.w + nc.w);
  }
  red[threadIdx.x] = fmaxf(1.0f - ps + ns, 0.0f);
  __syncthreads();
  for (int ofs = 128; ofs >= 1; ofs >>= 1) {
    if (threadIdx.x < ofs) red[threadIdx.x] += red[threadIdx.x + ofs];
    __syncthreads();
  }
  if (threadIdx.x == 0) unsafeAtomicAdd(acc_r, red[0]);
}

__global__ void finalize_kernel(const float* __restrict__ acc, float* __restrict__ out) {
  float lr = acc[0] / (float)BB;
  float ls = acc[1];
  out[0] = lr + LAM1 * ls;
  out[1] = lr;
  out[2] = ls;
}

// ===========================================================================
extern "C" void kernel_launch(void* const* d_in, const int* in_sizes, int n_in,
                              void* d_out, int out_size, void* d_ws, size_t ws_size,
                              hipStream_t stream) {
  const float* E_u_0   = (const float*)d_in[0];
  const float* E_i_0   = (const float*)d_in[1];
  const float* svd_u   = (const float*)d_in[2];
  const float* svd_v   = (const float*)d_in[3];
  const float* sdiag   = (const float*)d_in[4];
  const float* ut      = (const float*)d_in[5];
  const float* vt      = (const float*)d_in[6];
  const float* W_u     = (const float*)d_in[7];
  const float* W_i     = (const float*)d_in[8];
  const float* adjv    = (const float*)d_in[9];
  const float* dropr   = (const float*)d_in[10];
  const float* noise_u1= (const float*)d_in[11];
  const float* noise_v1= (const float*)d_in[12];
  const float* noise_u2= (const float*)d_in[13];
  const float* noise_v2= (const float*)d_in[14];
  const float* u_mask  = (const float*)d_in[15];
  const float* i_mask  = (const float*)d_in[16];
  const int*   rows    = (const int*)d_in[17];
  const int*   cols    = (const int*)d_in[18];
  const int*   uids    = (const int*)d_in[19];
  const int*   iids    = (const int*)d_in[20];
  const int*   pos     = (const int*)d_in[21];
  const int*   neg     = (const int*)d_in[22];
  float* out = (float*)d_out;

  // ---- workspace layout (~72 MB, with aliasing) ----
  float* ws     = (float*)d_ws;
  float* EU1    = ws;                           // 6,400,000
  float* EI1    = EU1 + (size_t)N_U * DD;       // 3,200,000
  float* vtei   = EI1 + (size_t)N_I * DD;       // 2*4096
  float* uteu   = vtei + 2 * DD * DD;           // 2*4096
  float* accs   = uteu + 2 * DD * DD;           // 16
  float* region = accs + 16;                    // 2,097,152 (time-shared)
  // phase A (gemm partials):
  float* CpA = region;
  float* CpB = region + (size_t)GEMM_BLOCKS * 4096;
  // phase B (post-gemm buffers):
  float* bu   = region;                          // 131072
  float* bpos = bu   + (size_t)BB * DD;          // 131072
  float* bneg = bpos + (size_t)BB * DD;          // 131072
  float* hu   = bneg + (size_t)BB * DD;          // 524288
  float* hv   = hu   + (size_t)4 * BB * DD;      // 524288
  float* negp = hv   + (size_t)4 * BB * DD;      // 262144 (sum 1,703,936 < 2,097,152)
  float* dvu1 = region + (size_t)2 * GEMM_BLOCKS * 4096; // 1,000,000
  float* dvu2 = dvu1 + NNZ_;                    // 1,000,000
  float* dvi1 = dvu2 + NNZ_;                    // 1,000,000
  float* dvi2 = dvi1 + NNZ_;                    // 1,000,000
  int* gat_u = (int*)(dvi2 + NNZ_);             // 1,000,000
  int* gat_i = gat_u + NNZ_;                    // 1,000,000
  int* off_u = gat_i + NNZ_;                    // 100,001
  int* off_i = off_u + (N_U + 1);               // 50,001
  int* cur_u = off_i + (N_I + 1);               // 100,000
  int* cur_i = cur_u + N_U;                     // 50,000
  int* spart = cur_i + N_I;                     // 256
  // scan temps alias edge-payload space (free until scatter_build):
  int* stmp  = (int*)dvu1;                      // <= N_U
  int* deg_u = (int*)dvu2;                      // N_U
  int* deg_i = deg_u + N_U;                     // N_I

  const int TB = 256;
  dim3 blk(TB);
  int eg = (NNZ_ + TB - 1) / TB;
  int row_grid = BB / 4;

  hipMemsetAsync(deg_u, 0, (size_t)(N_U + N_I) * sizeof(int), stream);
  hipMemsetAsync(cur_u, 0, (size_t)(N_U + N_I) * sizeof(int), stream);
  hipMemsetAsync(accs, 0, 16 * sizeof(float), stream);

  // ---- CSR build + edge payloads ----
  hist_kernel<<<eg, blk, 0, stream>>>(rows, cols, deg_u, deg_i, NNZ_);
  {
    int nb_u = (N_U + 1023) / 1024, nb_i = (N_I + 1023) / 1024;
    scan1<<<nb_u, blk, 0, stream>>>(deg_u, stmp, spart, N_U);
    scan2<<<1, blk, 0, stream>>>(spart, nb_u);
    scan3<<<(N_U + TB - 1) / TB, blk, 0, stream>>>(stmp, spart, off_u, N_U);
    scan1<<<nb_i, blk, 0, stream>>>(deg_i, stmp, spart, N_I);
    scan2<<<1, blk, 0, stream>>>(spart, nb_i);
    scan3<<<(N_I + TB - 1) / TB, blk, 0, stream>>>(stmp, spart, off_i, N_I);
  }
  scatter_build<<<eg, blk, 0, stream>>>(rows, cols, adjv, dropr, off_u, off_i,
                                        cur_u, cur_i, gat_u, gat_i,
                                        dvu1, dvu2, dvi1, dvi2, NNZ_);

  // ---- layer-1 small GEMMs ----
  gemm_dual<<<dim3(GEMM_BLOCKS, 2), blk, 0, stream>>>(vt, E_i_0, N_I, CpA,
                                                      ut, E_u_0, N_U, CpB);
  gemm_reduce_dual<<<dim3(16, 2), blk, 0, stream>>>(CpA, vtei, CpB, uteu);

  // ---- layer-1 full SpMM, both sides fused ----
  spmm_all<<<(N_U + N_I + 3) / 4, blk, 0, stream>>>(off_u, gat_u, dvu1,
                                                    off_i, gat_i, dvi1,
                                                    E_u_0, E_i_0, EU1, EI1);

  // ---- layer-2 small GEMMs ----
  gemm_dual<<<dim3(GEMM_BLOCKS, 2), blk, 0, stream>>>(vt, EI1, N_I, CpA,
                                                      ut, EU1, N_U, CpB);
  gemm_reduce_dual<<<dim3(16, 2), blk, 0, stream>>>(CpA, vtei + 4096, CpB, uteu + 4096);

  // ---- layer-2 SpMM at batch rows only (region now free for phase B) ----
  spmm_batch3<<<dim3(row_grid, 3), blk, 0, stream>>>(uids, pos, neg,
      off_u, gat_u, dvu2, off_i, gat_i, dvi2, EU1, EI1, bu, bpos, bneg);

  // ---- contrastive ----
  h_kernel2<<<dim3(row_grid, LL), blk, 0, stream>>>(svd_u, noise_u1, noise_u2, sdiag,
                                                    vtei, W_u, uids, hu);
  h_kernel2<<<dim3(row_grid, LL), blk, 0, stream>>>(svd_v, noise_v1, noise_v2, sdiag,
                                                    uteu, W_i, iids, hv);
  score_tiles<<<dim3(32, 32, 4), blk, 0, stream>>>(hu, hv, negp);
  score_loss<<<dim3(8, 4), blk, 0, stream>>>(hu, hv, negp, u_mask, i_mask, accs + 1);

  // ---- BPR ----
  bpr_kernel<<<8, blk, 0, stream>>>(E_u_0, EU1, bu, E_i_0, EI1, bpos, bneg,
                                    uids, pos, neg, accs);

  finalize_kernel<<<1, 1, 0, stream>>>(accs, out);
}

// Round 5
// 1039.058 us; speedup vs baseline: 4.5144x; 1.0118x over previous
//
#include <hip/hip_runtime.h>
#include <cstddef>

// ---- problem constants (from reference) ----
#define N_U   100000
#define N_I   50000
#define DD    64
#define NNZ_  1000000
#define LL    2
#define TEMP_ 0.2f
#define LAM1  0.2f
#define DROP_ 0.1f
#define EPS_  0.05f
#define BB    2048
#define KCH   512
#define NCH_I ((N_I + KCH - 1) / KCH)   /* 98  */
#define NCH_U ((N_U + KCH - 1) / KCH)   /* 196 */
#define REGION_SZ 2097152               /* floats, time-shared scratch */

__device__ __forceinline__ float leaky(float x) { return x >= 0.0f ? x : 0.5f * x; }

__device__ __forceinline__ float waveReduceSum(float v) {
#pragma unroll
  for (int m = 32; m >= 1; m >>= 1) v += __shfl_xor(v, m, 64);
  return v;
}

__device__ __forceinline__ int rlanei(int v, int l) {
  return __builtin_amdgcn_readlane(v, l);
}
__device__ __forceinline__ float rlanef(float v, int l) {
  return __int_as_float(__builtin_amdgcn_readlane(__float_as_int(v), l));
}

// ===========================================================================
// CSR build: histogram -> scan (3-phase) -> scatter (+ edge payload build)
// ===========================================================================
__global__ void hist_kernel(const int* __restrict__ rows, const int* __restrict__ cols,
                            int* __restrict__ deg_u, int* __restrict__ deg_i, int nnz) {
  int e = blockIdx.x * blockDim.x + threadIdx.x;
  if (e >= nnz) return;
  atomicAdd(&deg_u[rows[e]], 1);
  atomicAdd(&deg_i[cols[e]], 1);
}

__global__ void scan1(const int* __restrict__ in, int* __restrict__ tmp,
                      int* __restrict__ partial, int n) {
  __shared__ int s[256];
  int t = threadIdx.x;
  int base = blockIdx.x * 1024;
  int v[4]; int tsum = 0;
#pragma unroll
  for (int k = 0; k < 4; ++k) {
    int idx = base + t * 4 + k;
    v[k] = (idx < n) ? in[idx] : 0;
    tsum += v[k];
  }
  s[t] = tsum;
  __syncthreads();
  for (int ofs = 1; ofs < 256; ofs <<= 1) {
    int x = (t >= ofs) ? s[t - ofs] : 0;
    __syncthreads();
    s[t] += x;
    __syncthreads();
  }
  if (t == 255) partial[blockIdx.x] = s[255];
  int run = (t == 0) ? 0 : s[t - 1];
#pragma unroll
  for (int k = 0; k < 4; ++k) {
    run += v[k];
    int idx = base + t * 4 + k;
    if (idx < n) tmp[idx] = run;
  }
}

__global__ void scan2(int* __restrict__ partial, int nb) {
  __shared__ int s[256];
  int t = threadIdx.x;
  s[t] = (t < nb) ? partial[t] : 0;
  __syncthreads();
  for (int ofs = 1; ofs < 256; ofs <<= 1) {
    int x = (t >= ofs) ? s[t - ofs] : 0;
    __syncthreads();
    s[t] += x;
    __syncthreads();
  }
  if (t < nb) partial[t] = (t == 0) ? 0 : s[t - 1];
}

__global__ void scan3(const int* __restrict__ tmp, const int* __restrict__ partial,
                      int* __restrict__ off, int n) {
  int i = blockIdx.x * blockDim.x + threadIdx.x;
  if (i == 0) off[0] = 0;
  if (i < n) off[i + 1] = tmp[i] + partial[i >> 10];
}

__global__ void scatter_build(const int* __restrict__ rows, const int* __restrict__ cols,
                              const float* __restrict__ vals, const float* __restrict__ dropr,
                              const int* __restrict__ off_u, const int* __restrict__ off_i,
                              int* __restrict__ cur_u, int* __restrict__ cur_i,
                              int* __restrict__ gat_u, int* __restrict__ gat_i,
                              float* __restrict__ dvu1, float* __restrict__ dvu2,
                              float* __restrict__ dvi1, float* __restrict__ dvi2,
                              int nnz) {
  int e = blockIdx.x * blockDim.x + threadIdx.x;
  if (e >= nnz) return;
  int r = rows[e], c = cols[e];
  float v = vals[e] * (1.0f / (1.0f - DROP_));
  float k0 = (dropr[e] >= DROP_) ? v : 0.0f;
  float k1 = (dropr[(size_t)NNZ_ + e] >= DROP_) ? v : 0.0f;
  float k2 = (dropr[(size_t)2 * NNZ_ + e] >= DROP_) ? v : 0.0f;
  float k3 = (dropr[(size_t)3 * NNZ_ + e] >= DROP_) ? v : 0.0f;
  int p = off_u[r] + atomicAdd(&cur_u[r], 1);
  gat_u[p] = c; dvu1[p] = k0; dvu2[p] = k2;
  int q = off_i[c] + atomicAdd(&cur_i[c], 1);
  gat_i[q] = r; dvi1[q] = k1; dvi2[q] = k3;
}

// ===========================================================================
// Layer-1 SpMM, both sides in one launch. One wave per row; lane = dim.
// ===========================================================================
__global__ void spmm_all(const int* __restrict__ off_u, const int* __restrict__ gat_u,
                         const float* __restrict__ dvu,
                         const int* __restrict__ off_i, const int* __restrict__ gat_i,
                         const float* __restrict__ dvi,
                         const float* __restrict__ Eu0, const float* __restrict__ Ei0,
                         float* __restrict__ EU1, float* __restrict__ EI1) {
  int wid = threadIdx.x >> 6, lane = threadIdx.x & 63;
  int r = blockIdx.x * 4 + wid;
  const int* off; const int* gat; const float* dv;
  const float* Esrc; const float* base; float* out;
  if (r < N_U) {
    off = off_u; gat = gat_u; dv = dvu; Esrc = Ei0; base = Eu0; out = EU1;
  } else {
    r -= N_U;
    if (r >= N_I) return;
    off = off_i; gat = gat_i; dv = dvi; Esrc = Eu0; base = Ei0; out = EI1;
  }
  int i0 = off[r], i1 = off[r + 1];
  float acc = 0.0f;
  for (int p = i0; p < i1; p += 64) {
    int cn = min(64, i1 - p);
    float dvl = 0.0f; int gl = 0;
    if (lane < cn) { dvl = dv[p + lane]; gl = gat[p + lane]; }
    int j = 0;
    for (; j + 3 < cn; j += 4) {
      float d0 = rlanef(dvl, j), d1 = rlanef(dvl, j + 1),
            d2 = rlanef(dvl, j + 2), d3 = rlanef(dvl, j + 3);
      int g0 = rlanei(gl, j), g1 = rlanei(gl, j + 1),
          g2 = rlanei(gl, j + 2), g3 = rlanei(gl, j + 3);
      float e0 = Esrc[(size_t)g0 * DD + lane];
      float e1 = Esrc[(size_t)g1 * DD + lane];
      float e2 = Esrc[(size_t)g2 * DD + lane];
      float e3 = Esrc[(size_t)g3 * DD + lane];
      acc += d0 * e0; acc += d1 * e1; acc += d2 * e2; acc += d3 * e3;
    }
    for (; j < cn; ++j)
      acc += rlanef(dvl, j) * Esrc[(size_t)rlanei(gl, j) * DD + lane];
  }
  size_t o = (size_t)r * DD + lane;
  out[o] = base[o] + leaky(acc);
}

// Layer-2 SpMM only at gathered batch rows (uids | pos | neg via blockIdx.y).
__global__ void spmm_batch3(const int* __restrict__ uids, const int* __restrict__ pos,
                            const int* __restrict__ neg,
                            const int* __restrict__ off_u, const int* __restrict__ gat_u,
                            const float* __restrict__ dvu2,
                            const int* __restrict__ off_i, const int* __restrict__ gat_i,
                            const float* __restrict__ dvi2,
                            const float* __restrict__ EU1, const float* __restrict__ EI1,
                            float* __restrict__ bu, float* __restrict__ bpos,
                            float* __restrict__ bneg) {
  int z = blockIdx.y;
  const int* ids = (z == 0) ? uids : ((z == 1) ? pos : neg);
  const int* off = (z == 0) ? off_u : off_i;
  const int* gat = (z == 0) ? gat_u : gat_i;
  const float* dv = (z == 0) ? dvu2 : dvi2;
  const float* Esrc = (z == 0) ? EI1 : EU1;
  const float* base = (z == 0) ? EU1 : EI1;
  float* out = (z == 0) ? bu : ((z == 1) ? bpos : bneg);
  int wid = threadIdx.x >> 6, lane = threadIdx.x & 63;
  int i = blockIdx.x * 4 + wid;
  int r = ids[i];
  int i0 = off[r], i1 = off[r + 1];
  float acc = 0.0f;
  for (int p = i0; p < i1; p += 64) {
    int cn = min(64, i1 - p);
    float dvl = 0.0f; int gl = 0;
    if (lane < cn) { dvl = dv[p + lane]; gl = gat[p + lane]; }
    int j = 0;
    for (; j + 3 < cn; j += 4) {
      float d0 = rlanef(dvl, j), d1 = rlanef(dvl, j + 1),
            d2 = rlanef(dvl, j + 2), d3 = rlanef(dvl, j + 3);
      int g0 = rlanei(gl, j), g1 = rlanei(gl, j + 1),
          g2 = rlanei(gl, j + 2), g3 = rlanei(gl, j + 3);
      acc += d0 * Esrc[(size_t)g0 * DD + lane];
      acc += d1 * Esrc[(size_t)g1 * DD + lane];
      acc += d2 * Esrc[(size_t)g2 * DD + lane];
      acc += d3 * Esrc[(size_t)g3 * DD + lane];
    }
    for (; j < cn; ++j)
      acc += rlanef(dvl, j) * Esrc[(size_t)rlanei(gl, j) * DD + lane];
  }
  out[(size_t)i * DD + lane] = base[(size_t)r * DD + lane] + leaky(acc);
}

// ===========================================================================
// LDS-tiled dual GEMM: C[64][64] = A[64][N] @ B[N][64], outer-product 4x4
// register tiles; one K-chunk (KCH) per block; per-chunk partials, no atomics.
// Problems packed along blockIdx.x: [0,NCH_I) -> (A0,B0,N_I), rest -> (A1,B1,N_U)
// ===========================================================================
__global__ void gemm_tiled(const float* __restrict__ A0, const float* __restrict__ B0,
                           const float* __restrict__ A1, const float* __restrict__ B1,
                           float* __restrict__ Cp) {
  __shared__ float sA[64][68];
  __shared__ float sB[64][68];
  int bx = blockIdx.x;
  const float* A; const float* B; int N; int k0;
  if (bx < NCH_I) { A = A0; B = B0; N = N_I; k0 = bx * KCH; }
  else            { A = A1; B = B1; N = N_U; k0 = (bx - NCH_I) * KCH; }
  int t = threadIdx.x;
  int ti = t >> 4, tj = t & 15;
  float acc[4][4];
#pragma unroll
  for (int x = 0; x < 4; ++x)
#pragma unroll
    for (int y = 0; y < 4; ++y) acc[x][y] = 0.0f;

  for (int tt = 0; tt < KCH / 64; ++tt) {
    int kb = k0 + tt * 64;
    if (kb >= N) break;            // uniform across block (k0,N uniform)
    __syncthreads();
#pragma unroll
    for (int it = 0; it < 16; ++it) {
      int lin = t + it * 256;
      int r = lin >> 6, c = lin & 63;
      sA[r][c] = (kb + c < N) ? A[(size_t)r * N + kb + c] : 0.0f;          // A[r][k]
      sB[r][c] = (kb + r < N) ? B[(size_t)(kb + r) * DD + c] : 0.0f;       // B[k][d]
    }
    __syncthreads();
#pragma unroll 8
    for (int k = 0; k < 64; ++k) {
      float4 b = *(const float4*)&sB[k][tj * 4];
      float a0 = sA[ti * 4 + 0][k];
      float a1 = sA[ti * 4 + 1][k];
      float a2 = sA[ti * 4 + 2][k];
      float a3 = sA[ti * 4 + 3][k];
      acc[0][0] += a0 * b.x; acc[0][1] += a0 * b.y; acc[0][2] += a0 * b.z; acc[0][3] += a0 * b.w;
      acc[1][0] += a1 * b.x; acc[1][1] += a1 * b.y; acc[1][2] += a1 * b.z; acc[1][3] += a1 * b.w;
      acc[2][0] += a2 * b.x; acc[2][1] += a2 * b.y; acc[2][2] += a2 * b.z; acc[2][3] += a2 * b.w;
      acc[3][0] += a3 * b.x; acc[3][1] += a3 * b.y; acc[3][2] += a3 * b.z; acc[3][3] += a3 * b.w;
    }
  }
  float* cp = Cp + (size_t)bx * 4096;
#pragma unroll
  for (int x = 0; x < 4; ++x)
#pragma unroll
    for (int y = 0; y < 4; ++y)
      cp[(ti * 4 + x) * DD + tj * 4 + y] = acc[x][y];
}

// fold partials: y=0 -> problem0 (NCH_I partials) -> C0; y=1 -> C1.
__global__ void gemm_reduce2(const float* __restrict__ Cp,
                             float* __restrict__ C0, float* __restrict__ C1) {
  int y = blockIdx.y;
  const float* base = Cp + (y ? (size_t)NCH_I * 4096 : 0);
  int cnt = y ? NCH_U : NCH_I;
  float* C = y ? C1 : C0;
  int idx = blockIdx.x * 256 + threadIdx.x;
  float s = 0.0f;
  for (int b = 0; b < cnt; ++b) s += base[(size_t)b * 4096 + idx];
  C[idx] = s;
}

// ===========================================================================
// h for both views and both layers of one side. hout [layer][view][BB][64].
// ===========================================================================
__global__ void h_kernel2(const float* __restrict__ svd,
                          const float* __restrict__ n1, const float* __restrict__ n2,
                          const float* __restrict__ sdiag,
                          const float* __restrict__ Mb,
                          const float* __restrict__ Wb,
                          const int*   __restrict__ ids,
                          float*       __restrict__ hout) {
  int layer = blockIdx.y;
  const float* M = Mb + layer * 4096;
  const float* W = Wb + layer * 4096;
  int wid  = threadIdx.x >> 6;
  int lane = threadIdx.x & 63;
  int i = blockIdx.x * 4 + wid;
  int id = ids[i];
  float sv = svd[(size_t)id * DD + lane];
  float sgn = (sv > 0.0f) ? 1.0f : ((sv < 0.0f) ? -1.0f : 0.0f);
  float sd = sdiag[lane];

  float z1 = n1[(size_t)id * DD + lane];
  float z2 = n2[(size_t)id * DD + lane];
  float d1 = fmaxf(sqrtf(waveReduceSum(z1 * z1)), 1e-12f);
  float d2 = fmaxf(sqrtf(waveReduceSum(z2 * z2)), 1e-12f);
  float g1 = (sv + sgn * (z1 / d1) * EPS_) * sd;
  float g2 = (sv + sgn * (z2 / d2) * EPS_) * sd;

  float a1 = 0.0f, a2 = 0.0f;
#pragma unroll
  for (int k = 0; k < 64; ++k) {
    float m = M[k * DD + lane];
    a1 += rlanef(g1, k) * m;
    a2 += rlanef(g2, k) * m;
  }
  a1 = leaky(a1); a2 = leaky(a2);
  float s1 = fmaxf(sqrtf(waveReduceSum(a1 * a1)), 1e-12f);
  float s2 = fmaxf(sqrtf(waveReduceSum(a2 * a2)), 1e-12f);
  float gn1 = a1 / s1, gn2 = a2 / s2;

  float h1 = 0.0f, h2 = 0.0f;
#pragma unroll
  for (int k = 0; k < 64; ++k) {
    float w = W[k * DD + lane];
    h1 += rlanef(gn1, k) * w;
    h2 += rlanef(gn2, k) * w;
  }
  size_t b0 = ((size_t)(layer * 2 + 0) * BB + i) * DD + lane;
  size_t b1 = ((size_t)(layer * 2 + 1) * BB + i) * DD + lane;
  hout[b0] = h1;
  hout[b1] = h2;
}

// ===========================================================================
// score tiles: 64x64 tile of exp(S/T), row-sum partials (non-atomic)
// ===========================================================================
__global__ void score_tiles(const float* __restrict__ hu, const float* __restrict__ hv,
                            float* __restrict__ negpart) {
  __shared__ float s1[64][65];
  __shared__ float s2[64][65];
  int z = blockIdx.z;
  int layer = z >> 1, side = z & 1;
  const float* hb = side ? hv : hu;
  const float* h1 = hb + (size_t)(layer * 2 + 0) * BB * DD;
  const float* h2 = hb + (size_t)(layer * 2 + 1) * BB * DD;
  int i0 = blockIdx.x * 64, j0 = blockIdx.y * 64;
  int t = threadIdx.x;
#pragma unroll
  for (int k = 0; k < 16; ++k) {
    int lin = t + k * 256;
    int r = lin >> 6, c = lin & 63;
    s1[r][c] = h1[(size_t)(i0 + r) * DD + c];
    s2[r][c] = h2[(size_t)(j0 + r) * DD + c];
  }
  __syncthreads();
  int ti = t >> 4, tj = t & 15;
  float acc[4][4];
#pragma unroll
  for (int x = 0; x < 4; ++x)
#pragma unroll
    for (int y = 0; y < 4; ++y) acc[x][y] = 0.0f;
  for (int d = 0; d < 64; ++d) {
    float a[4], b[4];
#pragma unroll
    for (int k = 0; k < 4; ++k) { a[k] = s1[ti * 4 + k][d]; b[k] = s2[tj * 4 + k][d]; }
#pragma unroll
    for (int x = 0; x < 4; ++x)
#pragma unroll
      for (int y = 0; y < 4; ++y) acc[x][y] += a[x] * b[y];
  }
  float rsum[4];
#pragma unroll
  for (int x = 0; x < 4; ++x) {
    float s = 0.0f;
#pragma unroll
    for (int y = 0; y < 4; ++y) s += expf(acc[x][y] * (1.0f / TEMP_));
    rsum[x] = s;
  }
  __syncthreads();
#pragma unroll
  for (int x = 0; x < 4; ++x) s1[ti * 4 + x][tj] = rsum[x];
  __syncthreads();
  if (t < 64) {
    float s = 0.0f;
#pragma unroll
    for (int c = 0; c < 16; ++c) s += s1[t][c];
    negpart[((size_t)z * 32 + blockIdx.y) * BB + i0 + t] = s;
  }
}

__global__ void score_loss(const float* __restrict__ hu, const float* __restrict__ hv,
                           const float* __restrict__ negpart,
                           const float* __restrict__ u_mask, const float* __restrict__ i_mask,
                           float* __restrict__ loss_acc) {
  __shared__ float red[256];
  int z = blockIdx.y;
  int layer = z >> 1, side = z & 1;
  const float* hb = side ? hv : hu;
  const float* h1 = hb + (size_t)(layer * 2 + 0) * BB * DD;
  const float* h2 = hb + (size_t)(layer * 2 + 1) * BB * DD;
  const float* mask = (side ? i_mask : u_mask) + layer * BB;
  int i = blockIdx.x * 256 + threadIdx.x;
  const float4* a = (const float4*)(h1 + (size_t)i * DD);
  const float4* b = (const float4*)(h2 + (size_t)i * DD);
  float pos = 0.0f;
#pragma unroll
  for (int k = 0; k < 16; ++k) {
    float4 av = a[k], bv = b[k];
    pos += av.x * bv.x + av.y * bv.y + av.z * bv.z + av.w * bv.w;
  }
  float ng = 0.0f;
  for (int jt = 0; jt < 32; ++jt) ng += negpart[((size_t)z * 32 + jt) * BB + i];
  float ps = expf(pos * (1.0f / TEMP_));
  float m = (mask[i] > 0.5f) ? 1.0f : 0.0f;
  float li = -logf(ps / (ng + 1e-8f) + 1e-8f) * m;
  red[threadIdx.x] = li;
  __syncthreads();
  for (int ofs = 128; ofs >= 1; ofs >>= 1) {
    if (threadIdx.x < ofs) red[threadIdx.x] += red[threadIdx.x + ofs];
    __syncthreads();
  }
  if (threadIdx.x == 0) unsafeAtomicAdd(loss_acc, red[0]);
}

// ===========================================================================
// BPR
// ===========================================================================
__global__ void bpr_kernel(const float* __restrict__ Eu0, const float* __restrict__ EU1,
                           const float* __restrict__ bu,
                           const float* __restrict__ Ei0, const float* __restrict__ EI1,
                           const float* __restrict__ bpos, const float* __restrict__ bneg,
                           const int* __restrict__ uids, const int* __restrict__ pos,
                           const int* __restrict__ neg,
                           float* __restrict__ acc_r) {
  __shared__ float red[256];
  int i = blockIdx.x * 256 + threadIdx.x;
  const float4* u0 = (const float4*)(Eu0 + (size_t)uids[i] * DD);
  const float4* u1 = (const float4*)(EU1 + (size_t)uids[i] * DD);
  const float4* u2 = (const float4*)(bu  + (size_t)i * DD);
  const float4* p0 = (const float4*)(Ei0 + (size_t)pos[i] * DD);
  const float4* p1 = (const float4*)(EI1 + (size_t)pos[i] * DD);
  const float4* p2 = (const float4*)(bpos + (size_t)i * DD);
  const float4* n0 = (const float4*)(Ei0 + (size_t)neg[i] * DD);
  const float4* n1 = (const float4*)(EI1 + (size_t)neg[i] * DD);
  const float4* n2 = (const float4*)(bneg + (size_t)i * DD);
  float ps = 0.0f, ns = 0.0f;
#pragma unroll
  for (int k = 0; k < 16; ++k) {
    float4 ua = u0[k], ub = u1[k], uc = u2[k];
    float4 pa = p0[k], pb = p1[k], pc = p2[k];
    float4 na = n0[k], nb = n1[k], nc = n2[k];
    float ux = ua.x + ub.x + uc.x, uy = ua.y + ub.y + uc.y,
          uz = ua.z + ub.z + uc.z, uw = ua.w + ub.w + uc.w;
    ps += ux * (pa.x + pb.x + pc.x) + uy * (pa.y + pb.y + pc.y)
        + uz * (pa.z + pb.z + pc.z) + uw * (pa.w + pb.w + pc.w);
    ns += ux * (na.x + nb.x + nc.x) + uy * (na.y + nb.y + nc.y)
        + uz * (na.z + nb.z + nc.z) + uw * (na.w + nb.w + nc.w);
  }
  red[threadIdx.x] = fmaxf(1.0f - ps + ns, 0.0f);
  __syncthreads();
  for (int ofs = 128; ofs >= 1; ofs >>= 1) {
    if (threadIdx.x < ofs) red[threadIdx.x] += red[threadIdx.x + ofs];
    __syncthreads();
  }
  if (threadIdx.x == 0) unsafeAtomicAdd(acc_r, red[0]);
}

__global__ void finalize_kernel(const float* __restrict__ acc, float* __restrict__ out) {
  float lr = acc[0] / (float)BB;
  float ls = acc[1];
  out[0] = lr + LAM1 * ls;
  out[1] = lr;
  out[2] = ls;
}

// ===========================================================================
extern "C" void kernel_launch(void* const* d_in, const int* in_sizes, int n_in,
                              void* d_out, int out_size, void* d_ws, size_t ws_size,
                              hipStream_t stream) {
  const float* E_u_0   = (const float*)d_in[0];
  const float* E_i_0   = (const float*)d_in[1];
  const float* svd_u   = (const float*)d_in[2];
  const float* svd_v   = (const float*)d_in[3];
  const float* sdiag   = (const float*)d_in[4];
  const float* ut      = (const float*)d_in[5];
  const float* vt      = (const float*)d_in[6];
  const float* W_u     = (const float*)d_in[7];
  const float* W_i     = (const float*)d_in[8];
  const float* adjv    = (const float*)d_in[9];
  const float* dropr   = (const float*)d_in[10];
  const float* noise_u1= (const float*)d_in[11];
  const float* noise_v1= (const float*)d_in[12];
  const float* noise_u2= (const float*)d_in[13];
  const float* noise_v2= (const float*)d_in[14];
  const float* u_mask  = (const float*)d_in[15];
  const float* i_mask  = (const float*)d_in[16];
  const int*   rows    = (const int*)d_in[17];
  const int*   cols    = (const int*)d_in[18];
  const int*   uids    = (const int*)d_in[19];
  const int*   iids    = (const int*)d_in[20];
  const int*   pos     = (const int*)d_in[21];
  const int*   neg     = (const int*)d_in[22];
  float* out = (float*)d_out;

  // ---- workspace layout (~72 MB, with aliasing) ----
  float* ws     = (float*)d_ws;
  float* EU1    = ws;                           // 6,400,000
  float* EI1    = EU1 + (size_t)N_U * DD;       // 3,200,000
  float* vtei   = EI1 + (size_t)N_I * DD;       // 2*4096
  float* uteu   = vtei + 2 * DD * DD;           // 2*4096
  float* accs   = uteu + 2 * DD * DD;           // 16
  float* region = accs + 16;                    // REGION_SZ floats (time-shared)
  // phase A (gemm partials): (NCH_I+NCH_U)*4096 = 1,204,224 < REGION_SZ
  float* Cp   = region;
  // phase B (post-gemm buffers):
  float* bu   = region;                          // 131072
  float* bpos = bu   + (size_t)BB * DD;          // 131072
  float* bneg = bpos + (size_t)BB * DD;          // 131072
  float* hu   = bneg + (size_t)BB * DD;          // 524288
  float* hv   = hu   + (size_t)4 * BB * DD;      // 524288
  float* negp = hv   + (size_t)4 * BB * DD;      // 262144 (sum 1,703,936 < REGION_SZ)
  float* dvu1 = region + (size_t)REGION_SZ;      // 1,000,000
  float* dvu2 = dvu1 + NNZ_;                    // 1,000,000
  float* dvi1 = dvu2 + NNZ_;                    // 1,000,000
  float* dvi2 = dvi1 + NNZ_;                    // 1,000,000
  int* gat_u = (int*)(dvi2 + NNZ_);             // 1,000,000
  int* gat_i = gat_u + NNZ_;                    // 1,000,000
  int* off_u = gat_i + NNZ_;                    // 100,001
  int* off_i = off_u + (N_U + 1);               // 50,001
  int* cur_u = off_i + (N_I + 1);               // 100,000
  int* cur_i = cur_u + N_U;                     // 50,000
  int* spart = cur_i + N_I;                     // 256
  // scan temps alias edge-payload space (free until scatter_build):
  int* stmp  = (int*)dvu1;                      // <= N_U
  int* deg_u = (int*)dvu2;                      // N_U
  int* deg_i = deg_u + N_U;                     // N_I

  const int TB = 256;
  dim3 blk(TB);
  int eg = (NNZ_ + TB - 1) / TB;
  int row_grid = BB / 4;

  hipMemsetAsync(deg_u, 0, (size_t)(N_U + N_I) * sizeof(int), stream);
  hipMemsetAsync(cur_u, 0, (size_t)(N_U + N_I) * sizeof(int), stream);
  hipMemsetAsync(accs, 0, 16 * sizeof(float), stream);

  // ---- CSR build + edge payloads ----
  hist_kernel<<<eg, blk, 0, stream>>>(rows, cols, deg_u, deg_i, NNZ_);
  {
    int nb_u = (N_U + 1023) / 1024, nb_i = (N_I + 1023) / 1024;
    scan1<<<nb_u, blk, 0, stream>>>(deg_u, stmp, spart, N_U);
    scan2<<<1, blk, 0, stream>>>(spart, nb_u);
    scan3<<<(N_U + TB - 1) / TB, blk, 0, stream>>>(stmp, spart, off_u, N_U);
    scan1<<<nb_i, blk, 0, stream>>>(deg_i, stmp, spart, N_I);
    scan2<<<1, blk, 0, stream>>>(spart, nb_i);
    scan3<<<(N_I + TB - 1) / TB, blk, 0, stream>>>(stmp, spart, off_i, N_I);
  }
  scatter_build<<<eg, blk, 0, stream>>>(rows, cols, adjv, dropr, off_u, off_i,
                                        cur_u, cur_i, gat_u, gat_i,
                                        dvu1, dvu2, dvi1, dvi2, NNZ_);

  // ---- layer-1 small GEMMs (LDS-tiled outer-product, partials, reduce) ----
  gemm_tiled<<<NCH_I + NCH_U, blk, 0, stream>>>(vt, E_i_0, ut, E_u_0, Cp);
  gemm_reduce2<<<dim3(16, 2), blk, 0, stream>>>(Cp, vtei, uteu);

  // ---- layer-1 full SpMM, both sides fused ----
  spmm_all<<<(N_U + N_I + 3) / 4, blk, 0, stream>>>(off_u, gat_u, dvu1,
                                                    off_i, gat_i, dvi1,
                                                    E_u_0, E_i_0, EU1, EI1);

  // ---- layer-2 small GEMMs ----
  gemm_tiled<<<NCH_I + NCH_U, blk, 0, stream>>>(vt, EI1, ut, EU1, Cp);
  gemm_reduce2<<<dim3(16, 2), blk, 0, stream>>>(Cp, vtei + 4096, uteu + 4096);

  // ---- layer-2 SpMM at batch rows only (region now free for phase B) ----
  spmm_batch3<<<dim3(row_grid, 3), blk, 0, stream>>>(uids, pos, neg,
      off_u, gat_u, dvu2, off_i, gat_i, dvi2, EU1, EI1, bu, bpos, bneg);

  // ---- contrastive ----
  h_kernel2<<<dim3(row_grid, LL), blk, 0, stream>>>(svd_u, noise_u1, noise_u2, sdiag,
                                                    vtei, W_u, uids, hu);
  h_kernel2<<<dim3(row_grid, LL), blk, 0, stream>>>(svd_v, noise_v1, noise_v2, sdiag,
                                                    uteu, W_i, iids, hv);
  score_tiles<<<dim3(32, 32, 4), blk, 0, stream>>>(hu, hv, negp);
  score_loss<<<dim3(8, 4), blk, 0, stream>>>(hu, hv, negp, u_mask, i_mask, accs + 1);

  // ---- BPR ----
  bpr_kernel<<<8, blk, 0, stream>>>(E_u_0, EU1, bu, E_i_0, EI1, bpos, bneg,
                                    uids, pos, neg, accs);

  finalize_kernel<<<1, 1, 0, stream>>>(accs, out);
}